// Round 4
// baseline (673.689 us; speedup 1.0000x reference)
//
#include <hip/hip_runtime.h>

#define DM 1024
#define SEQ 2048
#define NH 16
#define DK 64

typedef __bf16 bf16x8 __attribute__((ext_vector_type(8)));
typedef float f32x4 __attribute__((ext_vector_type(4)));

__device__ inline unsigned short f2bf(float f) {
    unsigned u = __float_as_uint(f);
    u += 0x7fffu + ((u >> 16) & 1u);
    return (unsigned short)(u >> 16);
}

// fp32 -> bf16 for the four weight matrices (1M elems each), one dispatch.
__global__ __launch_bounds__(256) void cvt_w(const float* __restrict__ s0,
                                             const float* __restrict__ s1,
                                             const float* __restrict__ s2,
                                             const float* __restrict__ s3,
                                             unsigned short* __restrict__ d0,
                                             unsigned short* __restrict__ d1,
                                             unsigned short* __restrict__ d2,
                                             unsigned short* __restrict__ d3) {
    const float* s;
    unsigned short* d;
    switch (blockIdx.y) {
        case 0: s = s0; d = d0; break;
        case 1: s = s1; d = d1; break;
        case 2: s = s2; d = d2; break;
        default: s = s3; d = d3; break;
    }
    int i = (blockIdx.x * 256 + threadIdx.x) * 4;
    float4 v = *(const float4*)(s + i);
    ushort4 o;
    o.x = f2bf(v.x); o.y = f2bf(v.y); o.z = f2bf(v.z); o.w = f2bf(v.w);
    *(ushort4*)(d + i) = o;
}

// C[M,N] = A[M,K] @ W[N,K]^T + bias[N]
template <bool A_BF16, bool B_BF16, bool OUT_F32>
__global__ __launch_bounds__(256) void gemm_bt(const void* __restrict__ Av,
                                               const void* __restrict__ Wv,
                                               const float* __restrict__ bias,
                                               void* __restrict__ Cv,
                                               int M, int N, int K) {
    const int LDT = 40;  // padded bf16 row stride (32 + 8)
    __shared__ unsigned short lds_a[128 * LDT];
    __shared__ unsigned short lds_w[128 * LDT];

    const int t = threadIdx.x;
    const int lane = t & 63;
    const int w = t >> 6;
    const int wr = w >> 1, wc = w & 1;
    const int rowBase = blockIdx.x * 128;
    const int colBase = blockIdx.y * 128;
    const int l15 = lane & 15;
    const int lg = lane >> 4;

    f32x4 acc[4][4] = {};

    for (int k0 = 0; k0 < K; k0 += 32) {
#pragma unroll
        for (int i = 0; i < 4; ++i) {
            int slot = t + 256 * i;      // 0..1023, 8 slots of 4 elems per row
            int r = slot >> 3;
            int c4 = (slot & 7) * 4;
            ushort4 sv;
            if (A_BF16) {
                sv = *(const ushort4*)((const unsigned short*)Av +
                                       (size_t)(rowBase + r) * K + k0 + c4);
            } else {
                float4 vv = *(const float4*)((const float*)Av +
                                             (size_t)(rowBase + r) * K + k0 + c4);
                sv.x = f2bf(vv.x); sv.y = f2bf(vv.y); sv.z = f2bf(vv.z); sv.w = f2bf(vv.w);
            }
            *(ushort4*)&lds_a[r * LDT + c4] = sv;

            ushort4 swv;
            if (B_BF16) {
                swv = *(const ushort4*)((const unsigned short*)Wv +
                                        (size_t)(colBase + r) * K + k0 + c4);
            } else {
                float4 wv2 = *(const float4*)((const float*)Wv +
                                              (size_t)(colBase + r) * K + k0 + c4);
                swv.x = f2bf(wv2.x); swv.y = f2bf(wv2.y); swv.z = f2bf(wv2.z); swv.w = f2bf(wv2.w);
            }
            *(ushort4*)&lds_w[r * LDT + c4] = swv;
        }
        __syncthreads();

        const unsigned short* pa = &lds_a[(wr * 64 + l15) * LDT + lg * 8];
        const unsigned short* pw = &lds_w[(wc * 64 + l15) * LDT + lg * 8];
        bf16x8 af[4], wf[4];
#pragma unroll
        for (int m = 0; m < 4; ++m) af[m] = *(const bf16x8*)(pa + m * 16 * LDT);
#pragma unroll
        for (int n = 0; n < 4; ++n) wf[n] = *(const bf16x8*)(pw + n * 16 * LDT);
#pragma unroll
        for (int m = 0; m < 4; ++m)
#pragma unroll
            for (int n = 0; n < 4; ++n)
                acc[m][n] = __builtin_amdgcn_mfma_f32_16x16x32_bf16(af[m], wf[n],
                                                                    acc[m][n], 0, 0, 0);
        __syncthreads();
    }

#pragma unroll
    for (int m = 0; m < 4; ++m) {
        int row = rowBase + wr * 64 + m * 16 + lg * 4;
#pragma unroll
        for (int n = 0; n < 4; ++n) {
            int col = colBase + wc * 64 + n * 16 + l15;
            float bv = bias[col];
#pragma unroll
            for (int j = 0; j < 4; ++j) {
                float val = acc[m][n][j] + bv;
                if (OUT_F32)
                    ((float*)Cv)[(size_t)(row + j) * N + col] = val;
                else
                    ((unsigned short*)Cv)[(size_t)(row + j) * N + col] = f2bf(val);
            }
        }
    }
}

// V [B,S, H*64] bf16  ->  Vt [B*H, 64, S] bf16
__global__ __launch_bounds__(256) void transpose_v(const unsigned short* __restrict__ V,
                                                   unsigned short* __restrict__ Vt) {
    __shared__ unsigned short tile[64][65];
    int s0 = blockIdx.x * 64;
    int bh = blockIdx.y;
    int b = bh >> 4, h = bh & 15;
    int t = threadIdx.x;
#pragma unroll
    for (int i = 0; i < 8; ++i) {
        int slot = t + 256 * i;
        int s = slot >> 5;
        int d2 = (slot & 31) * 2;
        const unsigned short* src = V + (size_t)(b * SEQ + s0 + s) * DM + h * DK + d2;
        ushort2 v = *(const ushort2*)src;
        tile[s][d2] = v.x;
        tile[s][d2 + 1] = v.y;
    }
    __syncthreads();
#pragma unroll
    for (int i = 0; i < 8; ++i) {
        int slot = t + 256 * i;
        int d = slot >> 5;
        int s2 = (slot & 31) * 2;
        ushort2 v;
        v.x = tile[s2][d];
        v.y = tile[s2 + 1][d];
        unsigned short* dst = Vt + (size_t)(bh * DK + d) * SEQ + s0 + s2;
        *(ushort2*)dst = v;
    }
}

// Flash attention, causal, swapped-operand, kv-split 2x.
// Wave pair (half=0/1) splits each q-tile's kv range; partials merged via LDS.
// grid (32, 64): 8192 waves == device capacity, uniform ~32.5 kv-tiles each.
__global__ __launch_bounds__(256, 8) void attn(const unsigned short* __restrict__ Q,
                                               const unsigned short* __restrict__ K,
                                               const unsigned short* __restrict__ Vt,
                                               unsigned short* __restrict__ X) {
    __shared__ unsigned short p_lds[4][16 * 40];  // per-wave P^T tile [16q][32kv+pad]
    __shared__ float mrg_acc[2][16][64];          // per-pair partner acc
    __shared__ float mrg_ml[2][2][64];            // per-pair partner m, l
    const int t = threadIdx.x;
    const int lane = t & 63;
    const int w = t >> 6;
    const int l15 = lane & 15, lg = lane >> 4;
    const int bh = blockIdx.y;
    const int b = bh >> 4, h = bh & 15;
    const int pairIdx = w >> 1, half = w & 1;
    const int p = blockIdx.x * 2 + pairIdx;  // pair id 0..63
    unsigned short* pl = &p_lds[w][0];

    for (int task = 0; task < 2; ++task) {
        const int qt = task ? 127 - p : p;  // 16-row q-tile index 0..127
        const int qrow0 = qt * 16;
        const int qg = qrow0 + l15;

        const size_t qoff = (size_t)(b * SEQ + qrow0 + l15) * DM + h * DK + lg * 8;
        const bf16x8 qf0 = *(const bf16x8*)(Q + qoff);
        const bf16x8 qf1 = *(const bf16x8*)(Q + qoff + 32);

        f32x4 acc[4] = {};
        float m = -1e30f, lsum = 0.f;
        const int nt = ((qrow0 + 15) >> 5) + 1;
        const int nth = nt >> 1;
        const int tBeg = half ? nth : 0;
        const int tEnd = half ? nt : nth;

        for (int tile = tBeg; tile < tEnd; ++tile) {
            const int kv0 = tile << 5;

            bf16x8 kf[2][2];
#pragma unroll
            for (int s = 0; s < 2; ++s) {
                const size_t koff =
                    (size_t)(b * SEQ + kv0 + s * 16 + l15) * DM + h * DK + lg * 8;
                kf[s][0] = *(const bf16x8*)(K + koff);
                kf[s][1] = *(const bf16x8*)(K + koff + 32);
            }
            bf16x8 vf[4];
#pragma unroll
            for (int d = 0; d < 4; ++d) {
                const size_t voff = (size_t)(bh * DK + d * 16 + l15) * SEQ + kv0 + lg * 8;
                vf[d] = *(const bf16x8*)(Vt + voff);
            }

            // swapped QK^T: S^T[kv][q], lane holds col q=l15, rows kv = s*16+4*lg+j
            float sv[8];
#pragma unroll
            for (int s = 0; s < 2; ++s) {
                f32x4 st = {};
                st = __builtin_amdgcn_mfma_f32_16x16x32_bf16(kf[s][0], qf0, st, 0, 0, 0);
                st = __builtin_amdgcn_mfma_f32_16x16x32_bf16(kf[s][1], qf1, st, 0, 0, 0);
#pragma unroll
                for (int j = 0; j < 4; ++j) sv[s * 4 + j] = st[j] * 0.125f;
            }
            if (kv0 + 31 > qrow0) {  // only diagonal tiles mask
#pragma unroll
                for (int s = 0; s < 2; ++s)
#pragma unroll
                    for (int j = 0; j < 4; ++j) {
                        int kvg = kv0 + s * 16 + 4 * lg + j;
                        if (kvg > qg) sv[s * 4 + j] = -1e30f;
                    }
            }

            float tm = sv[0];
#pragma unroll
            for (int r = 1; r < 8; ++r) tm = fmaxf(tm, sv[r]);
            tm = fmaxf(tm, __shfl_xor(tm, 16, 64));
            tm = fmaxf(tm, __shfl_xor(tm, 32, 64));

            const float newm = fmaxf(m, tm);
            const float al = __expf(m - newm);
            m = newm;
            float ps[8], ts = 0.f;
#pragma unroll
            for (int r = 0; r < 8; ++r) {
                ps[r] = __expf(sv[r] - newm);
                ts += ps[r];
            }
            ts += __shfl_xor(ts, 16, 64);
            ts += __shfl_xor(ts, 32, 64);
            lsum = lsum * al + ts;
#pragma unroll
            for (int d = 0; d < 4; ++d)
#pragma unroll
                for (int j = 0; j < 4; ++j) acc[d][j] *= al;

#pragma unroll
            for (int s = 0; s < 2; ++s) {
                ushort4 pk;
                pk.x = f2bf(ps[s * 4 + 0]);
                pk.y = f2bf(ps[s * 4 + 1]);
                pk.z = f2bf(ps[s * 4 + 2]);
                pk.w = f2bf(ps[s * 4 + 3]);
                *(ushort4*)&pl[l15 * 40 + s * 16 + 4 * lg] = pk;
            }
            const bf16x8 pf = *(const bf16x8*)&pl[l15 * 40 + lg * 8];

#pragma unroll
            for (int d = 0; d < 4; ++d)
                acc[d] = __builtin_amdgcn_mfma_f32_16x16x32_bf16(vf[d], pf, acc[d], 0, 0, 0);
        }

        // merge partials across the wave pair
        __syncthreads();
        if (half == 1) {
#pragma unroll
            for (int d = 0; d < 4; ++d)
#pragma unroll
                for (int j = 0; j < 4; ++j) mrg_acc[pairIdx][d * 4 + j][lane] = acc[d][j];
            mrg_ml[pairIdx][0][lane] = m;
            mrg_ml[pairIdx][1][lane] = lsum;
        }
        __syncthreads();
        if (half == 0) {
            const float m1 = mrg_ml[pairIdx][0][lane];
            const float l1 = mrg_ml[pairIdx][1][lane];
            const float M = fmaxf(m, m1);
            const float a0 = __expf(m - M);
            const float a1 = __expf(m1 - M);
            const float inv = 1.0f / (a0 * lsum + a1 * l1);
#pragma unroll
            for (int d = 0; d < 4; ++d) {
                ushort4 o;
#pragma unroll
                for (int j = 0; j < 4; ++j) {
                    float val = (a0 * acc[d][j] + a1 * mrg_acc[pairIdx][d * 4 + j][lane]) * inv;
                    ((unsigned short*)&o)[j] = f2bf(val);
                }
                *(ushort4*)&X[(size_t)(b * SEQ + qg) * DM + h * DK + d * 16 + 4 * lg] = o;
            }
        }
        __syncthreads();
    }
}

extern "C" void kernel_launch(void* const* d_in, const int* in_sizes, int n_in,
                              void* d_out, int out_size, void* d_ws, size_t ws_size,
                              hipStream_t stream) {
    const float* q  = (const float*)d_in[0];
    const float* k  = (const float*)d_in[1];
    const float* v  = (const float*)d_in[2];
    const float* Wq = (const float*)d_in[4];
    const float* bq = (const float*)d_in[5];
    const float* Wk = (const float*)d_in[6];
    const float* bk = (const float*)d_in[7];
    const float* Wv = (const float*)d_in[8];
    const float* bv = (const float*)d_in[9];
    const float* Wo = (const float*)d_in[10];
    const float* bo = (const float*)d_in[11];

    const size_t NEL = (size_t)4 * SEQ * DM;  // 8,388,608 elems per buffer
    const size_t WEL = (size_t)DM * DM;       // 1,048,576 elems per weight
    unsigned short* Qp  = (unsigned short*)d_ws;
    unsigned short* Kp  = Qp + NEL;
    unsigned short* Vp  = Kp + NEL;
    unsigned short* Vt  = Vp + NEL;
    unsigned short* Wob = Vt + NEL;   // ws total: 4*NEL + WEL ushorts (~69 MB)
    unsigned short* Xp  = Vp;         // reuse V's slot after transpose
    // Wq/Wk/Wv bf16 live in d_out scratch (overwritten by the final GEMM)
    unsigned short* Wqb = (unsigned short*)d_out;
    unsigned short* Wkb = Wqb + WEL;
    unsigned short* Wvb = Wkb + WEL;

    dim3 gg(64, 8), gb(256);
    hipLaunchKernelGGL(cvt_w, dim3(1024, 4), gb, 0, stream, Wq, Wk, Wv, Wo, Wqb, Wkb, Wvb, Wob);
    hipLaunchKernelGGL((gemm_bt<false, true, false>), gg, gb, 0, stream, (const void*)q, (const void*)Wqb, bq, (void*)Qp, 8192, DM, DM);
    hipLaunchKernelGGL((gemm_bt<false, true, false>), gg, gb, 0, stream, (const void*)k, (const void*)Wkb, bk, (void*)Kp, 8192, DM, DM);
    hipLaunchKernelGGL((gemm_bt<false, true, false>), gg, gb, 0, stream, (const void*)v, (const void*)Wvb, bv, (void*)Vp, 8192, DM, DM);
    hipLaunchKernelGGL(transpose_v, dim3(32, 64), gb, 0, stream, Vp, Vt);
    hipLaunchKernelGGL(attn, dim3(32, 64), gb, 0, stream, Qp, Kp, Vt, Xp);
    hipLaunchKernelGGL((gemm_bt<true, true, true>), gg, gb, 0, stream, (const void*)Xp, (const void*)Wob, bo, d_out, 8192, DM, DM);
}

// Round 5
// 404.314 us; speedup vs baseline: 1.6663x; 1.6663x over previous
//
#include <hip/hip_runtime.h>

#define DM 1024
#define SEQ 2048
#define NH 16
#define DK 64

typedef __bf16 bf16x8 __attribute__((ext_vector_type(8)));
typedef float f32x4 __attribute__((ext_vector_type(4)));

__device__ inline unsigned short f2bf(float f) {
    unsigned u = __float_as_uint(f);
    u += 0x7fffu + ((u >> 16) & 1u);
    return (unsigned short)(u >> 16);
}

// fp32 -> bf16 for the four weight matrices (1M elems each), one dispatch.
__global__ __launch_bounds__(256) void cvt_w(const float* __restrict__ s0,
                                             const float* __restrict__ s1,
                                             const float* __restrict__ s2,
                                             const float* __restrict__ s3,
                                             unsigned short* __restrict__ d0,
                                             unsigned short* __restrict__ d1,
                                             unsigned short* __restrict__ d2,
                                             unsigned short* __restrict__ d3) {
    const float* s;
    unsigned short* d;
    switch (blockIdx.y) {
        case 0: s = s0; d = d0; break;
        case 1: s = s1; d = d1; break;
        case 2: s = s2; d = d2; break;
        default: s = s3; d = d3; break;
    }
    int i = (blockIdx.x * 256 + threadIdx.x) * 4;
    float4 v = *(const float4*)(s + i);
    ushort4 o;
    o.x = f2bf(v.x); o.y = f2bf(v.y); o.z = f2bf(v.z); o.w = f2bf(v.w);
    *(ushort4*)(d + i) = o;
}

// C[M,N] = A[M,K] @ W[N,K]^T + bias[N]
template <bool A_BF16, bool B_BF16, bool OUT_F32>
__global__ __launch_bounds__(256) void gemm_bt(const void* __restrict__ Av,
                                               const void* __restrict__ Wv,
                                               const float* __restrict__ bias,
                                               void* __restrict__ Cv,
                                               int M, int N, int K) {
    const int LDT = 40;  // padded bf16 row stride (32 + 8)
    __shared__ unsigned short lds_a[128 * LDT];
    __shared__ unsigned short lds_w[128 * LDT];

    const int t = threadIdx.x;
    const int lane = t & 63;
    const int w = t >> 6;
    const int wr = w >> 1, wc = w & 1;
    const int rowBase = blockIdx.x * 128;
    const int colBase = blockIdx.y * 128;
    const int l15 = lane & 15;
    const int lg = lane >> 4;

    f32x4 acc[4][4] = {};

    for (int k0 = 0; k0 < K; k0 += 32) {
#pragma unroll
        for (int i = 0; i < 4; ++i) {
            int slot = t + 256 * i;      // 0..1023, 8 slots of 4 elems per row
            int r = slot >> 3;
            int c4 = (slot & 7) * 4;
            ushort4 sv;
            if (A_BF16) {
                sv = *(const ushort4*)((const unsigned short*)Av +
                                       (size_t)(rowBase + r) * K + k0 + c4);
            } else {
                float4 vv = *(const float4*)((const float*)Av +
                                             (size_t)(rowBase + r) * K + k0 + c4);
                sv.x = f2bf(vv.x); sv.y = f2bf(vv.y); sv.z = f2bf(vv.z); sv.w = f2bf(vv.w);
            }
            *(ushort4*)&lds_a[r * LDT + c4] = sv;

            ushort4 swv;
            if (B_BF16) {
                swv = *(const ushort4*)((const unsigned short*)Wv +
                                        (size_t)(colBase + r) * K + k0 + c4);
            } else {
                float4 wv2 = *(const float4*)((const float*)Wv +
                                              (size_t)(colBase + r) * K + k0 + c4);
                swv.x = f2bf(wv2.x); swv.y = f2bf(wv2.y); swv.z = f2bf(wv2.z); swv.w = f2bf(wv2.w);
            }
            *(ushort4*)&lds_w[r * LDT + c4] = swv;
        }
        __syncthreads();

        const unsigned short* pa = &lds_a[(wr * 64 + l15) * LDT + lg * 8];
        const unsigned short* pw = &lds_w[(wc * 64 + l15) * LDT + lg * 8];
        bf16x8 af[4], wf[4];
#pragma unroll
        for (int m = 0; m < 4; ++m) af[m] = *(const bf16x8*)(pa + m * 16 * LDT);
#pragma unroll
        for (int n = 0; n < 4; ++n) wf[n] = *(const bf16x8*)(pw + n * 16 * LDT);
#pragma unroll
        for (int m = 0; m < 4; ++m)
#pragma unroll
            for (int n = 0; n < 4; ++n)
                acc[m][n] = __builtin_amdgcn_mfma_f32_16x16x32_bf16(af[m], wf[n],
                                                                    acc[m][n], 0, 0, 0);
        __syncthreads();
    }

#pragma unroll
    for (int m = 0; m < 4; ++m) {
        int row = rowBase + wr * 64 + m * 16 + lg * 4;
#pragma unroll
        for (int n = 0; n < 4; ++n) {
            int col = colBase + wc * 64 + n * 16 + l15;
            float bv = bias[col];
#pragma unroll
            for (int j = 0; j < 4; ++j) {
                float val = acc[m][n][j] + bv;
                if (OUT_F32)
                    ((float*)Cv)[(size_t)(row + j) * N + col] = val;
                else
                    ((unsigned short*)Cv)[(size_t)(row + j) * N + col] = f2bf(val);
            }
        }
    }
}

// V [B,S, H*64] bf16  ->  Vt [B*H, 64, S] bf16
__global__ __launch_bounds__(256) void transpose_v(const unsigned short* __restrict__ V,
                                                   unsigned short* __restrict__ Vt) {
    __shared__ unsigned short tile[64][65];
    int s0 = blockIdx.x * 64;
    int bh = blockIdx.y;
    int b = bh >> 4, h = bh & 15;
    int t = threadIdx.x;
#pragma unroll
    for (int i = 0; i < 8; ++i) {
        int slot = t + 256 * i;
        int s = slot >> 5;
        int d2 = (slot & 31) * 2;
        const unsigned short* src = V + (size_t)(b * SEQ + s0 + s) * DM + h * DK + d2;
        ushort2 v = *(const ushort2*)src;
        tile[s][d2] = v.x;
        tile[s][d2 + 1] = v.y;
    }
    __syncthreads();
#pragma unroll
    for (int i = 0; i < 8; ++i) {
        int slot = t + 256 * i;
        int d = slot >> 5;
        int s2 = (slot & 31) * 2;
        ushort2 v;
        v.x = tile[s2][d];
        v.y = tile[s2 + 1][d];
        unsigned short* dst = Vt + (size_t)(bh * DK + d) * SEQ + s0 + s2;
        *(ushort2*)dst = v;
    }
}

// Flash attention, causal, swapped-operand, kv-split 2x.
// Wave pair (half=0/1) splits each q-tile's kv range; partials merged via LDS.
// grid (32, 64): 8192 waves == device capacity, uniform ~32.5 kv-tiles each.
// NOTE: no min-waves in launch_bounds — (256,8) capped VGPR at 32 and spilled
// (FETCH 1.5 GB of scratch traffic, round 4). Natural allocation ~56-64 VGPR
// gives 8 waves/SIMD anyway.
__global__ __launch_bounds__(256) void attn(const unsigned short* __restrict__ Q,
                                            const unsigned short* __restrict__ K,
                                            const unsigned short* __restrict__ Vt,
                                            unsigned short* __restrict__ X) {
    __shared__ unsigned short p_lds[4][16 * 40];  // per-wave P^T tile [16q][32kv+pad]
    __shared__ float mrg_acc[2][16][64];          // per-pair partner acc
    __shared__ float mrg_ml[2][2][64];            // per-pair partner m, l
    const int t = threadIdx.x;
    const int lane = t & 63;
    const int w = t >> 6;
    const int l15 = lane & 15, lg = lane >> 4;
    const int bh = blockIdx.y;
    const int b = bh >> 4, h = bh & 15;
    const int pairIdx = w >> 1, half = w & 1;
    const int p = blockIdx.x * 2 + pairIdx;  // pair id 0..63
    unsigned short* pl = &p_lds[w][0];

    for (int task = 0; task < 2; ++task) {
        const int qt = task ? 127 - p : p;  // 16-row q-tile index 0..127
        const int qrow0 = qt * 16;
        const int qg = qrow0 + l15;

        const size_t qoff = (size_t)(b * SEQ + qrow0 + l15) * DM + h * DK + lg * 8;
        const bf16x8 qf0 = *(const bf16x8*)(Q + qoff);
        const bf16x8 qf1 = *(const bf16x8*)(Q + qoff + 32);

        f32x4 acc[4] = {};
        float m = -1e30f, lsum = 0.f;
        const int nt = ((qrow0 + 15) >> 5) + 1;
        const int nth = nt >> 1;
        const int tBeg = half ? nth : 0;
        const int tEnd = half ? nt : nth;

        for (int tile = tBeg; tile < tEnd; ++tile) {
            const int kv0 = tile << 5;

            bf16x8 kf[2][2];
#pragma unroll
            for (int s = 0; s < 2; ++s) {
                const size_t koff =
                    (size_t)(b * SEQ + kv0 + s * 16 + l15) * DM + h * DK + lg * 8;
                kf[s][0] = *(const bf16x8*)(K + koff);
                kf[s][1] = *(const bf16x8*)(K + koff + 32);
            }
            bf16x8 vf[4];
#pragma unroll
            for (int d = 0; d < 4; ++d) {
                const size_t voff = (size_t)(bh * DK + d * 16 + l15) * SEQ + kv0 + lg * 8;
                vf[d] = *(const bf16x8*)(Vt + voff);
            }

            // swapped QK^T: S^T[kv][q], lane holds col q=l15, rows kv = s*16+4*lg+j
            float sv[8];
#pragma unroll
            for (int s = 0; s < 2; ++s) {
                f32x4 st = {};
                st = __builtin_amdgcn_mfma_f32_16x16x32_bf16(kf[s][0], qf0, st, 0, 0, 0);
                st = __builtin_amdgcn_mfma_f32_16x16x32_bf16(kf[s][1], qf1, st, 0, 0, 0);
#pragma unroll
                for (int j = 0; j < 4; ++j) sv[s * 4 + j] = st[j] * 0.125f;
            }
            if (kv0 + 31 > qrow0) {  // only diagonal tiles mask
#pragma unroll
                for (int s = 0; s < 2; ++s)
#pragma unroll
                    for (int j = 0; j < 4; ++j) {
                        int kvg = kv0 + s * 16 + 4 * lg + j;
                        if (kvg > qg) sv[s * 4 + j] = -1e30f;
                    }
            }

            float tm = sv[0];
#pragma unroll
            for (int r = 1; r < 8; ++r) tm = fmaxf(tm, sv[r]);
            tm = fmaxf(tm, __shfl_xor(tm, 16, 64));
            tm = fmaxf(tm, __shfl_xor(tm, 32, 64));

            const float newm = fmaxf(m, tm);
            const float al = __expf(m - newm);
            m = newm;
            float ps[8], ts = 0.f;
#pragma unroll
            for (int r = 0; r < 8; ++r) {
                ps[r] = __expf(sv[r] - newm);
                ts += ps[r];
            }
            ts += __shfl_xor(ts, 16, 64);
            ts += __shfl_xor(ts, 32, 64);
            lsum = lsum * al + ts;
#pragma unroll
            for (int d = 0; d < 4; ++d)
#pragma unroll
                for (int j = 0; j < 4; ++j) acc[d][j] *= al;

#pragma unroll
            for (int s = 0; s < 2; ++s) {
                ushort4 pk;
                pk.x = f2bf(ps[s * 4 + 0]);
                pk.y = f2bf(ps[s * 4 + 1]);
                pk.z = f2bf(ps[s * 4 + 2]);
                pk.w = f2bf(ps[s * 4 + 3]);
                *(ushort4*)&pl[l15 * 40 + s * 16 + 4 * lg] = pk;
            }
            const bf16x8 pf = *(const bf16x8*)&pl[l15 * 40 + lg * 8];

#pragma unroll
            for (int d = 0; d < 4; ++d)
                acc[d] = __builtin_amdgcn_mfma_f32_16x16x32_bf16(vf[d], pf, acc[d], 0, 0, 0);
        }

        // merge partials across the wave pair
        __syncthreads();
        if (half == 1) {
#pragma unroll
            for (int d = 0; d < 4; ++d)
#pragma unroll
                for (int j = 0; j < 4; ++j) mrg_acc[pairIdx][d * 4 + j][lane] = acc[d][j];
            mrg_ml[pairIdx][0][lane] = m;
            mrg_ml[pairIdx][1][lane] = lsum;
        }
        __syncthreads();
        if (half == 0) {
            const float m1 = mrg_ml[pairIdx][0][lane];
            const float l1 = mrg_ml[pairIdx][1][lane];
            const float M = fmaxf(m, m1);
            const float a0 = __expf(m - M);
            const float a1 = __expf(m1 - M);
            const float inv = 1.0f / (a0 * lsum + a1 * l1);
#pragma unroll
            for (int d = 0; d < 4; ++d) {
                ushort4 o;
#pragma unroll
                for (int j = 0; j < 4; ++j) {
                    float val = (a0 * acc[d][j] + a1 * mrg_acc[pairIdx][d * 4 + j][lane]) * inv;
                    ((unsigned short*)&o)[j] = f2bf(val);
                }
                *(ushort4*)&X[(size_t)(b * SEQ + qg) * DM + h * DK + d * 16 + 4 * lg] = o;
            }
        }
        __syncthreads();
    }
}

extern "C" void kernel_launch(void* const* d_in, const int* in_sizes, int n_in,
                              void* d_out, int out_size, void* d_ws, size_t ws_size,
                              hipStream_t stream) {
    const float* q  = (const float*)d_in[0];
    const float* k  = (const float*)d_in[1];
    const float* v  = (const float*)d_in[2];
    const float* Wq = (const float*)d_in[4];
    const float* bq = (const float*)d_in[5];
    const float* Wk = (const float*)d_in[6];
    const float* bk = (const float*)d_in[7];
    const float* Wv = (const float*)d_in[8];
    const float* bv = (const float*)d_in[9];
    const float* Wo = (const float*)d_in[10];
    const float* bo = (const float*)d_in[11];

    const size_t NEL = (size_t)4 * SEQ * DM;  // 8,388,608 elems per buffer
    const size_t WEL = (size_t)DM * DM;       // 1,048,576 elems per weight
    unsigned short* Qp  = (unsigned short*)d_ws;
    unsigned short* Kp  = Qp + NEL;
    unsigned short* Vp  = Kp + NEL;
    unsigned short* Vt  = Vp + NEL;
    unsigned short* Wob = Vt + NEL;   // ws total: 4*NEL + WEL ushorts (~69 MB)
    unsigned short* Xp  = Vp;         // reuse V's slot after transpose
    // Wq/Wk/Wv bf16 live in d_out scratch (overwritten by the final GEMM)
    unsigned short* Wqb = (unsigned short*)d_out;
    unsigned short* Wkb = Wqb + WEL;
    unsigned short* Wvb = Wkb + WEL;

    dim3 gg(64, 8), gb(256);
    hipLaunchKernelGGL(cvt_w, dim3(1024, 4), gb, 0, stream, Wq, Wk, Wv, Wo, Wqb, Wkb, Wvb, Wob);
    hipLaunchKernelGGL((gemm_bt<false, true, false>), gg, gb, 0, stream, (const void*)q, (const void*)Wqb, bq, (void*)Qp, 8192, DM, DM);
    hipLaunchKernelGGL((gemm_bt<false, true, false>), gg, gb, 0, stream, (const void*)k, (const void*)Wkb, bk, (void*)Kp, 8192, DM, DM);
    hipLaunchKernelGGL((gemm_bt<false, true, false>), gg, gb, 0, stream, (const void*)v, (const void*)Wvb, bv, (void*)Vp, 8192, DM, DM);
    hipLaunchKernelGGL(transpose_v, dim3(32, 64), gb, 0, stream, Vp, Vt);
    hipLaunchKernelGGL(attn, dim3(32, 64), gb, 0, stream, Qp, Kp, Vt, Xp);
    hipLaunchKernelGGL((gemm_bt<true, true, true>), gg, gb, 0, stream, (const void*)Xp, (const void*)Wob, bo, d_out, 8192, DM, DM);
}

// Round 6
// 400.712 us; speedup vs baseline: 1.6812x; 1.0090x over previous
//
#include <hip/hip_runtime.h>

#define DM 1024
#define SEQ 2048
#define NH 16
#define DK 64

typedef __bf16 bf16x8 __attribute__((ext_vector_type(8)));
typedef float f32x4 __attribute__((ext_vector_type(4)));

__device__ inline unsigned short f2bf(float f) {
    unsigned u = __float_as_uint(f);
    u += 0x7fffu + ((u >> 16) & 1u);
    return (unsigned short)(u >> 16);
}

// fp32 -> bf16 for the four weight matrices (1M elems each), one dispatch.
__global__ __launch_bounds__(256) void cvt_w(const float* __restrict__ s0,
                                             const float* __restrict__ s1,
                                             const float* __restrict__ s2,
                                             const float* __restrict__ s3,
                                             unsigned short* __restrict__ d0,
                                             unsigned short* __restrict__ d1,
                                             unsigned short* __restrict__ d2,
                                             unsigned short* __restrict__ d3) {
    const float* s;
    unsigned short* d;
    switch (blockIdx.y) {
        case 0: s = s0; d = d0; break;
        case 1: s = s1; d = d1; break;
        case 2: s = s2; d = d2; break;
        default: s = s3; d = d3; break;
    }
    int i = (blockIdx.x * 256 + threadIdx.x) * 4;
    float4 v = *(const float4*)(s + i);
    ushort4 o;
    o.x = f2bf(v.x); o.y = f2bf(v.y); o.z = f2bf(v.z); o.w = f2bf(v.w);
    *(ushort4*)(d + i) = o;
}

// C[M,N] = A[M,K] @ W[N,K]^T + bias[N]
template <bool A_BF16, bool B_BF16, bool OUT_F32>
__global__ __launch_bounds__(256) void gemm_bt(const void* __restrict__ Av,
                                               const void* __restrict__ Wv,
                                               const float* __restrict__ bias,
                                               void* __restrict__ Cv,
                                               int M, int N, int K) {
    const int LDT = 40;  // padded bf16 row stride (32 + 8)
    __shared__ unsigned short lds_a[128 * LDT];
    __shared__ unsigned short lds_w[128 * LDT];

    const int t = threadIdx.x;
    const int lane = t & 63;
    const int w = t >> 6;
    const int wr = w >> 1, wc = w & 1;
    const int rowBase = blockIdx.x * 128;
    const int colBase = blockIdx.y * 128;
    const int l15 = lane & 15;
    const int lg = lane >> 4;

    f32x4 acc[4][4] = {};

    for (int k0 = 0; k0 < K; k0 += 32) {
#pragma unroll
        for (int i = 0; i < 4; ++i) {
            int slot = t + 256 * i;      // 0..1023, 8 slots of 4 elems per row
            int r = slot >> 3;
            int c4 = (slot & 7) * 4;
            ushort4 sv;
            if (A_BF16) {
                sv = *(const ushort4*)((const unsigned short*)Av +
                                       (size_t)(rowBase + r) * K + k0 + c4);
            } else {
                float4 vv = *(const float4*)((const float*)Av +
                                             (size_t)(rowBase + r) * K + k0 + c4);
                sv.x = f2bf(vv.x); sv.y = f2bf(vv.y); sv.z = f2bf(vv.z); sv.w = f2bf(vv.w);
            }
            *(ushort4*)&lds_a[r * LDT + c4] = sv;

            ushort4 swv;
            if (B_BF16) {
                swv = *(const ushort4*)((const unsigned short*)Wv +
                                        (size_t)(colBase + r) * K + k0 + c4);
            } else {
                float4 wv2 = *(const float4*)((const float*)Wv +
                                              (size_t)(colBase + r) * K + k0 + c4);
                swv.x = f2bf(wv2.x); swv.y = f2bf(wv2.y); swv.z = f2bf(wv2.z); swv.w = f2bf(wv2.w);
            }
            *(ushort4*)&lds_w[r * LDT + c4] = swv;
        }
        __syncthreads();

        const unsigned short* pa = &lds_a[(wr * 64 + l15) * LDT + lg * 8];
        const unsigned short* pw = &lds_w[(wc * 64 + l15) * LDT + lg * 8];
        bf16x8 af[4], wf[4];
#pragma unroll
        for (int m = 0; m < 4; ++m) af[m] = *(const bf16x8*)(pa + m * 16 * LDT);
#pragma unroll
        for (int n = 0; n < 4; ++n) wf[n] = *(const bf16x8*)(pw + n * 16 * LDT);
#pragma unroll
        for (int m = 0; m < 4; ++m)
#pragma unroll
            for (int n = 0; n < 4; ++n)
                acc[m][n] = __builtin_amdgcn_mfma_f32_16x16x32_bf16(af[m], wf[n],
                                                                    acc[m][n], 0, 0, 0);
        __syncthreads();
    }

#pragma unroll
    for (int m = 0; m < 4; ++m) {
        int row = rowBase + wr * 64 + m * 16 + lg * 4;
#pragma unroll
        for (int n = 0; n < 4; ++n) {
            int col = colBase + wc * 64 + n * 16 + l15;
            float bv = bias[col];
#pragma unroll
            for (int j = 0; j < 4; ++j) {
                float val = acc[m][n][j] + bv;
                if (OUT_F32)
                    ((float*)Cv)[(size_t)(row + j) * N + col] = val;
                else
                    ((unsigned short*)Cv)[(size_t)(row + j) * N + col] = f2bf(val);
            }
        }
    }
}

// V [B,S, H*64] bf16  ->  Vt [B*H, 64, S] bf16
__global__ __launch_bounds__(256) void transpose_v(const unsigned short* __restrict__ V,
                                                   unsigned short* __restrict__ Vt) {
    __shared__ unsigned short tile[64][65];
    int s0 = blockIdx.x * 64;
    int bh = blockIdx.y;
    int b = bh >> 4, h = bh & 15;
    int t = threadIdx.x;
#pragma unroll
    for (int i = 0; i < 8; ++i) {
        int slot = t + 256 * i;
        int s = slot >> 5;
        int d2 = (slot & 31) * 2;
        const unsigned short* src = V + (size_t)(b * SEQ + s0 + s) * DM + h * DK + d2;
        ushort2 v = *(const ushort2*)src;
        tile[s][d2] = v.x;
        tile[s][d2 + 1] = v.y;
    }
    __syncthreads();
#pragma unroll
    for (int i = 0; i < 8; ++i) {
        int slot = t + 256 * i;
        int d = slot >> 5;
        int s2 = (slot & 31) * 2;
        ushort2 v;
        v.x = tile[s2][d];
        v.y = tile[s2 + 1][d];
        unsigned short* dst = Vt + (size_t)(bh * DK + d) * SEQ + s0 + s2;
        *(ushort2*)dst = v;
    }
}

// Flash attention, causal, swapped-operand. ZERO LDS, zero barriers.
// - cross-tile K prefetch (ping-pong kA/kB, static unroll)
// - P^T redistribution in registers: 2-stage butterfly (shfl_xor 32 then 16)
//   moving score-fragment words to B-fragment layout B[k=8*lg+i][q=l15]
// - pair-tasking (qt, 127-qt) for causal balance
// - bijective XCD-chunked swizzle: contiguous bh range per XCD (K/V L2-hot)
__global__ __launch_bounds__(256) void attn(const unsigned short* __restrict__ Q,
                                            const unsigned short* __restrict__ K,
                                            const unsigned short* __restrict__ Vt,
                                            unsigned short* __restrict__ X) {
    const int t = threadIdx.x;
    const int lane = t & 63;
    const int w = t >> 6;
    const int l15 = lane & 15, lg = lane >> 4;
    const int c4 = (lane >> 4) & 1, c5 = (lane >> 5) & 1;

    // XCD-chunk swizzle: 1024 blocks, 8 XCDs, 128 blocks/XCD -> 8 bh per XCD
    const int orig = blockIdx.x;
    const int flat = (orig & 7) * 128 + (orig >> 3);
    const int bh = flat >> 4;
    const int p = (flat & 15) * 4 + w;  // pair id 0..63
    const int b = bh >> 4, h = bh & 15;

    const unsigned short* Qb = Q + (size_t)b * SEQ * DM + h * DK;
    const unsigned short* Kb = K + (size_t)b * SEQ * DM + h * DK;
    const unsigned short* Vb = Vt + (size_t)bh * DK * SEQ;
    const float SC = 0.125f * 1.44269504f;  // /sqrt(64) * log2(e), exp2 domain

    for (int task = 0; task < 2; ++task) {
        const int qt = task ? 127 - p : p;  // 16-row q-tile index 0..127
        const int qrow0 = qt * 16;
        const int qg = qrow0 + l15;

        const bf16x8 qf0 = *(const bf16x8*)(Qb + (size_t)(qrow0 + l15) * DM + lg * 8);
        const bf16x8 qf1 = *(const bf16x8*)(Qb + (size_t)(qrow0 + l15) * DM + lg * 8 + 32);

        f32x4 acc[4] = {};
        float m = -1e30f, lsum = 0.f;
        const int nt = (qt >> 1) + 1;  // 32-kv tiles

        bf16x8 kA[4], kB[4];

        auto LOADK = [&](bf16x8* kf, int tile) {
            const int kv0 = tile << 5;
#pragma unroll
            for (int s = 0; s < 2; ++s) {
                const unsigned short* kp = Kb + (size_t)(kv0 + s * 16 + l15) * DM + lg * 8;
                kf[s * 2 + 0] = *(const bf16x8*)kp;
                kf[s * 2 + 1] = *(const bf16x8*)(kp + 32);
            }
        };

        auto COMPUTE = [&](const bf16x8* kf, int tile) {
            const int kv0 = tile << 5;
            // V for this tile: needed only after softmax (~500cy) -> self-hiding
            bf16x8 vf[4];
#pragma unroll
            for (int d = 0; d < 4; ++d)
                vf[d] = *(const bf16x8*)(Vb + (size_t)(d * 16 + l15) * SEQ + kv0 + lg * 8);

            // swapped QK^T: lane holds S^T[kv=16s+4lg+j][q=l15]
            f32x4 st0 = {}, st1 = {};
            st0 = __builtin_amdgcn_mfma_f32_16x16x32_bf16(kf[0], qf0, st0, 0, 0, 0);
            st0 = __builtin_amdgcn_mfma_f32_16x16x32_bf16(kf[1], qf1, st0, 0, 0, 0);
            st1 = __builtin_amdgcn_mfma_f32_16x16x32_bf16(kf[2], qf0, st1, 0, 0, 0);
            st1 = __builtin_amdgcn_mfma_f32_16x16x32_bf16(kf[3], qf1, st1, 0, 0, 0);

            float sv[8];
#pragma unroll
            for (int j = 0; j < 4; ++j) {
                sv[j] = st0[j] * SC;
                sv[4 + j] = st1[j] * SC;
            }
            if (kv0 + 31 > qrow0) {  // wave-uniform: only diagonal tiles mask
#pragma unroll
                for (int s = 0; s < 2; ++s)
#pragma unroll
                    for (int j = 0; j < 4; ++j)
                        if (kv0 + s * 16 + 4 * lg + j > qg) sv[s * 4 + j] = -1e30f;
            }

            float tm = sv[0];
#pragma unroll
            for (int r = 1; r < 8; ++r) tm = fmaxf(tm, sv[r]);
            tm = fmaxf(tm, __shfl_xor(tm, 16, 64));
            tm = fmaxf(tm, __shfl_xor(tm, 32, 64));

            const float newm = fmaxf(m, tm);
            const float al = exp2f(m - newm);
            m = newm;
            float ps[8], ts = 0.f;
#pragma unroll
            for (int r = 0; r < 8; ++r) {
                ps[r] = exp2f(sv[r] - newm);
                ts += ps[r];
            }
            ts += __shfl_xor(ts, 16, 64);
            ts += __shfl_xor(ts, 32, 64);
            lsum = lsum * al + ts;
#pragma unroll
            for (int d = 0; d < 4; ++d)
#pragma unroll
                for (int j = 0; j < 4; ++j) acc[d][j] *= al;

            // pack P^T words: wsp[s][p2] = kv {16s+4lg+2p2, +1} (low, high)
            unsigned wsp[2][2];
#pragma unroll
            for (int s = 0; s < 2; ++s)
#pragma unroll
                for (int p2 = 0; p2 < 2; ++p2)
                    wsp[s][p2] = (unsigned)f2bf(ps[s * 4 + 2 * p2]) |
                                 ((unsigned)f2bf(ps[s * 4 + 2 * p2 + 1]) << 16);

            // stage A: swap kv-bit4 (word s) with lane-bit5
            unsigned n0[2], n1[2];
#pragma unroll
            for (int p2 = 0; p2 < 2; ++p2) {
                unsigned snd = c5 ? wsp[0][p2] : wsp[1][p2];
                unsigned exch = __shfl_xor((int)snd, 32, 64);
                n0[p2] = c5 ? exch : wsp[0][p2];
                n1[p2] = c5 ? wsp[1][p2] : exch;
            }
            // stage B: swap kv-bit3 (word x) with lane-bit4
            unsigned f0[2], f1[2];
#pragma unroll
            for (int p2 = 0; p2 < 2; ++p2) {
                unsigned snd = c4 ? n0[p2] : n1[p2];
                unsigned exch = __shfl_xor((int)snd, 16, 64);
                f0[p2] = c4 ? exch : n0[p2];
                f1[p2] = c4 ? n1[p2] : exch;
            }
            union { unsigned u[4]; bf16x8 v; } pu;
            pu.u[0] = f0[0]; pu.u[1] = f0[1]; pu.u[2] = f1[0]; pu.u[3] = f1[1];

            // PV: O^T = V^T . P^T
#pragma unroll
            for (int d = 0; d < 4; ++d)
                acc[d] = __builtin_amdgcn_mfma_f32_16x16x32_bf16(vf[d], pu.v, acc[d], 0, 0, 0);
        };

        LOADK(kA, 0);
        int tile = 0;
        while (true) {
            if (tile + 1 < nt) LOADK(kB, tile + 1);
            COMPUTE(kA, tile);
            if (++tile == nt) break;
            if (tile + 1 < nt) LOADK(kA, tile + 1);
            COMPUTE(kB, tile);
            if (++tile == nt) break;
        }

        const float inv = 1.0f / lsum;
#pragma unroll
        for (int d = 0; d < 4; ++d) {
            ushort4 o;
            o.x = f2bf(acc[d][0] * inv);
            o.y = f2bf(acc[d][1] * inv);
            o.z = f2bf(acc[d][2] * inv);
            o.w = f2bf(acc[d][3] * inv);
            *(ushort4*)&X[(size_t)(b * SEQ + qg) * DM + h * DK + d * 16 + 4 * lg] = o;
        }
    }
}

extern "C" void kernel_launch(void* const* d_in, const int* in_sizes, int n_in,
                              void* d_out, int out_size, void* d_ws, size_t ws_size,
                              hipStream_t stream) {
    const float* q  = (const float*)d_in[0];
    const float* k  = (const float*)d_in[1];
    const float* v  = (const float*)d_in[2];
    const float* Wq = (const float*)d_in[4];
    const float* bq = (const float*)d_in[5];
    const float* Wk = (const float*)d_in[6];
    const float* bk = (const float*)d_in[7];
    const float* Wv = (const float*)d_in[8];
    const float* bv = (const float*)d_in[9];
    const float* Wo = (const float*)d_in[10];
    const float* bo = (const float*)d_in[11];

    const size_t NEL = (size_t)4 * SEQ * DM;  // 8,388,608 elems per buffer
    const size_t WEL = (size_t)DM * DM;       // 1,048,576 elems per weight
    unsigned short* Qp  = (unsigned short*)d_ws;
    unsigned short* Kp  = Qp + NEL;
    unsigned short* Vp  = Kp + NEL;
    unsigned short* Vt  = Vp + NEL;
    unsigned short* Wob = Vt + NEL;   // ws total: 4*NEL + WEL ushorts (~69 MB)
    unsigned short* Xp  = Vp;         // reuse V's slot after transpose
    // Wq/Wk/Wv bf16 live in d_out scratch (overwritten by the final GEMM)
    unsigned short* Wqb = (unsigned short*)d_out;
    unsigned short* Wkb = Wqb + WEL;
    unsigned short* Wvb = Wkb + WEL;

    dim3 gg(64, 8), gb(256);
    hipLaunchKernelGGL(cvt_w, dim3(1024, 4), gb, 0, stream, Wq, Wk, Wv, Wo, Wqb, Wkb, Wvb, Wob);
    hipLaunchKernelGGL((gemm_bt<false, true, false>), gg, gb, 0, stream, (const void*)q, (const void*)Wqb, bq, (void*)Qp, 8192, DM, DM);
    hipLaunchKernelGGL((gemm_bt<false, true, false>), gg, gb, 0, stream, (const void*)k, (const void*)Wkb, bk, (void*)Kp, 8192, DM, DM);
    hipLaunchKernelGGL((gemm_bt<false, true, false>), gg, gb, 0, stream, (const void*)v, (const void*)Wvb, bv, (void*)Vp, 8192, DM, DM);
    hipLaunchKernelGGL(transpose_v, dim3(32, 64), gb, 0, stream, Vp, Vt);
    hipLaunchKernelGGL(attn, dim3(1024), gb, 0, stream, Qp, Kp, Vt, Xp);
    hipLaunchKernelGGL((gemm_bt<true, true, true>), gg, gb, 0, stream, (const void*)Xp, (const void*)Wob, bo, d_out, 8192, DM, DM);
}

// Round 7
// 279.625 us; speedup vs baseline: 2.4093x; 1.4330x over previous
//
#include <hip/hip_runtime.h>

#define DM 1024
#define SEQ 2048
#define NH 16
#define DK 64

typedef __bf16 bf16x8 __attribute__((ext_vector_type(8)));
typedef float f32x4 __attribute__((ext_vector_type(4)));

__device__ inline unsigned short f2bf(float f) {
    unsigned u = __float_as_uint(f);
    u += 0x7fffu + ((u >> 16) & 1u);
    return (unsigned short)(u >> 16);
}

// fp32 -> bf16 for the four weight matrices (1M elems each), one dispatch.
__global__ __launch_bounds__(256) void cvt_w(const float* __restrict__ s0,
                                             const float* __restrict__ s1,
                                             const float* __restrict__ s2,
                                             const float* __restrict__ s3,
                                             unsigned short* __restrict__ d0,
                                             unsigned short* __restrict__ d1,
                                             unsigned short* __restrict__ d2,
                                             unsigned short* __restrict__ d3) {
    const float* s;
    unsigned short* d;
    switch (blockIdx.y) {
        case 0: s = s0; d = d0; break;
        case 1: s = s1; d = d1; break;
        case 2: s = s2; d = d2; break;
        default: s = s3; d = d3; break;
    }
    int i = (blockIdx.x * 256 + threadIdx.x) * 4;
    float4 v = *(const float4*)(s + i);
    ushort4 o;
    o.x = f2bf(v.x); o.y = f2bf(v.y); o.z = f2bf(v.z); o.w = f2bf(v.w);
    *(ushort4*)(d + i) = o;
}

// C[M,N] = A[M,K] @ W[N,K]^T + bias[N]
template <bool A_BF16, bool B_BF16, bool OUT_F32>
__global__ __launch_bounds__(256) void gemm_bt(const void* __restrict__ Av,
                                               const void* __restrict__ Wv,
                                               const float* __restrict__ bias,
                                               void* __restrict__ Cv,
                                               int M, int N, int K) {
    const int LDT = 40;  // padded bf16 row stride (32 + 8)
    __shared__ unsigned short lds_a[128 * LDT];
    __shared__ unsigned short lds_w[128 * LDT];

    const int t = threadIdx.x;
    const int lane = t & 63;
    const int w = t >> 6;
    const int wr = w >> 1, wc = w & 1;
    const int rowBase = blockIdx.x * 128;
    const int colBase = blockIdx.y * 128;
    const int l15 = lane & 15;
    const int lg = lane >> 4;

    f32x4 acc[4][4] = {};

    for (int k0 = 0; k0 < K; k0 += 32) {
#pragma unroll
        for (int i = 0; i < 4; ++i) {
            int slot = t + 256 * i;      // 0..1023, 8 slots of 4 elems per row
            int r = slot >> 3;
            int c4 = (slot & 7) * 4;
            ushort4 sv;
            if (A_BF16) {
                sv = *(const ushort4*)((const unsigned short*)Av +
                                       (size_t)(rowBase + r) * K + k0 + c4);
            } else {
                float4 vv = *(const float4*)((const float*)Av +
                                             (size_t)(rowBase + r) * K + k0 + c4);
                sv.x = f2bf(vv.x); sv.y = f2bf(vv.y); sv.z = f2bf(vv.z); sv.w = f2bf(vv.w);
            }
            *(ushort4*)&lds_a[r * LDT + c4] = sv;

            ushort4 swv;
            if (B_BF16) {
                swv = *(const ushort4*)((const unsigned short*)Wv +
                                        (size_t)(colBase + r) * K + k0 + c4);
            } else {
                float4 wv2 = *(const float4*)((const float*)Wv +
                                              (size_t)(colBase + r) * K + k0 + c4);
                swv.x = f2bf(wv2.x); swv.y = f2bf(wv2.y); swv.z = f2bf(wv2.z); swv.w = f2bf(wv2.w);
            }
            *(ushort4*)&lds_w[r * LDT + c4] = swv;
        }
        __syncthreads();

        const unsigned short* pa = &lds_a[(wr * 64 + l15) * LDT + lg * 8];
        const unsigned short* pw = &lds_w[(wc * 64 + l15) * LDT + lg * 8];
        bf16x8 af[4], wf[4];
#pragma unroll
        for (int m = 0; m < 4; ++m) af[m] = *(const bf16x8*)(pa + m * 16 * LDT);
#pragma unroll
        for (int n = 0; n < 4; ++n) wf[n] = *(const bf16x8*)(pw + n * 16 * LDT);
#pragma unroll
        for (int m = 0; m < 4; ++m)
#pragma unroll
            for (int n = 0; n < 4; ++n)
                acc[m][n] = __builtin_amdgcn_mfma_f32_16x16x32_bf16(af[m], wf[n],
                                                                    acc[m][n], 0, 0, 0);
        __syncthreads();
    }

#pragma unroll
    for (int m = 0; m < 4; ++m) {
        int row = rowBase + wr * 64 + m * 16 + lg * 4;
#pragma unroll
        for (int n = 0; n < 4; ++n) {
            int col = colBase + wc * 64 + n * 16 + l15;
            float bv = bias[col];
#pragma unroll
            for (int j = 0; j < 4; ++j) {
                float val = acc[m][n][j] + bv;
                if (OUT_F32)
                    ((float*)Cv)[(size_t)(row + j) * N + col] = val;
                else
                    ((unsigned short*)Cv)[(size_t)(row + j) * N + col] = f2bf(val);
            }
        }
    }
}

// V [B,S, H*64] bf16  ->  Vt [B*H, 64, S] bf16
__global__ __launch_bounds__(256) void transpose_v(const unsigned short* __restrict__ V,
                                                   unsigned short* __restrict__ Vt) {
    __shared__ unsigned short tile[64][65];
    int s0 = blockIdx.x * 64;
    int bh = blockIdx.y;
    int b = bh >> 4, h = bh & 15;
    int t = threadIdx.x;
#pragma unroll
    for (int i = 0; i < 8; ++i) {
        int slot = t + 256 * i;
        int s = slot >> 5;
        int d2 = (slot & 31) * 2;
        const unsigned short* src = V + (size_t)(b * SEQ + s0 + s) * DM + h * DK + d2;
        ushort2 v = *(const ushort2*)src;
        tile[s][d2] = v.x;
        tile[s][d2 + 1] = v.y;
    }
    __syncthreads();
#pragma unroll
    for (int i = 0; i < 8; ++i) {
        int slot = t + 256 * i;
        int d = slot >> 5;
        int s2 = (slot & 31) * 2;
        ushort2 v;
        v.x = tile[s2][d];
        v.y = tile[s2 + 1][d];
        unsigned short* dst = Vt + (size_t)(bh * DK + d) * SEQ + s0 + s2;
        *(ushort2*)dst = v;
    }
}

// Flash attention, causal, swapped-operand, LDS-staged K/V (shared by 4 waves).
// Block: 4 waves x 16 q-rows = 64 q-rows; KVBLK=64; pair-tasking (qt, 31-qt)
// -> 33 uniform kv-steps/block. Staging is T14-split: coalesced 128B-row
// global loads -> regs one step early; ds_write after barrier. K/V LDS rows
// are 128B => XOR-swizzle col8^=(row&7)*8 on BOTH write and read (T2).
__global__ __launch_bounds__(256) void attn(const unsigned short* __restrict__ Q,
                                            const unsigned short* __restrict__ K,
                                            const unsigned short* __restrict__ Vt,
                                            unsigned short* __restrict__ X) {
    __shared__ unsigned short k_lds[64 * 64];  // [kv][d], swizzled
    __shared__ unsigned short v_lds[64 * 64];  // [d][kv] (V^T rows), swizzled

    const int t = threadIdx.x;
    const int lane = t & 63;
    const int w = t >> 6;
    const int l15 = lane & 15, lg = lane >> 4;
    const int c4 = (lane >> 4) & 1, c5 = (lane >> 5) & 1;

    // XCD-chunk swizzle: 1024 blocks, 128/XCD -> 8 bh (all 16 pairs) per XCD
    const int orig = blockIdx.x;
    const int flat = (orig & 7) * 128 + (orig >> 3);
    const int bh = flat >> 4;
    const int pr = flat & 15;  // pair id 0..15
    const int b = bh >> 4, h = bh & 15;

    const unsigned short* Qb = Q + (size_t)b * SEQ * DM + h * DK;
    const unsigned short* Kb = K + (size_t)b * SEQ * DM + h * DK;
    const unsigned short* Vb = Vt + (size_t)bh * DK * SEQ;
    const float SC = 0.125f * 1.44269504f;  // /sqrt(64) * log2(e)

    // staging geometry: 8 lanes per row (128B contiguous), 32 rows per pass
    const int sr = t >> 3;            // 0..31
    const int sc8 = (t & 7) * 8;      // col in bf16 elems
    const int sxo = (sr & 7) * 8;     // swizzle (same for sr and sr+32)
    const int xork = (l15 & 7) * 8;   // read-side swizzle

    bf16x8 kr0, kr1, vr0, vr1;

    for (int task = 0; task < 2; ++task) {
        const int qt = task ? 31 - pr : pr;  // 64-row q-tile index 0..31
        const int q0 = qt * 64;
        const int qrow0 = q0 + w * 16;
        const int qg = qrow0 + l15;

        const bf16x8 qf0 = *(const bf16x8*)(Qb + (size_t)(qrow0 + l15) * DM + lg * 8);
        const bf16x8 qf1 = *(const bf16x8*)(Qb + (size_t)(qrow0 + l15) * DM + lg * 8 + 32);

        f32x4 acc[4] = {};
        float m = -1e30f, lsum = 0.f;
        const int nt = qt + 1;  // 64-kv tiles

        // prologue stage-load tile 0
        {
            const int kv0 = 0;
            kr0 = *(const bf16x8*)(Kb + (size_t)(kv0 + sr) * DM + sc8);
            kr1 = *(const bf16x8*)(Kb + (size_t)(kv0 + 32 + sr) * DM + sc8);
            vr0 = *(const bf16x8*)(Vb + (size_t)sr * SEQ + kv0 + sc8);
            vr1 = *(const bf16x8*)(Vb + (size_t)(32 + sr) * SEQ + kv0 + sc8);
        }

        for (int tile = 0; tile < nt; ++tile) {
            const int kv0 = tile << 6;
            __syncthreads();  // everyone done reading LDS from prev step
            *(bf16x8*)&k_lds[sr * 64 + (sc8 ^ sxo)] = kr0;
            *(bf16x8*)&k_lds[(sr + 32) * 64 + (sc8 ^ sxo)] = kr1;
            *(bf16x8*)&v_lds[sr * 64 + (sc8 ^ sxo)] = vr0;
            *(bf16x8*)&v_lds[(sr + 32) * 64 + (sc8 ^ sxo)] = vr1;
            __syncthreads();  // tile ready

            if (tile + 1 < nt) {  // issue next-tile loads; hide under compute
                const int kn = (tile + 1) << 6;
                kr0 = *(const bf16x8*)(Kb + (size_t)(kn + sr) * DM + sc8);
                kr1 = *(const bf16x8*)(Kb + (size_t)(kn + 32 + sr) * DM + sc8);
                vr0 = *(const bf16x8*)(Vb + (size_t)sr * SEQ + kn + sc8);
                vr1 = *(const bf16x8*)(Vb + (size_t)(32 + sr) * SEQ + kn + sc8);
            }

            // QK^T swapped: st[s] = S^T[kv=16s+4lg+j][q=l15], s=0..3
            f32x4 st[4];
#pragma unroll
            for (int s = 0; s < 4; ++s) {
                const int rb = (s * 16 + l15) * 64;
                bf16x8 ka = *(const bf16x8*)&k_lds[rb + ((lg * 8) ^ xork)];
                bf16x8 kb2 = *(const bf16x8*)&k_lds[rb + ((32 + lg * 8) ^ xork)];
                f32x4 z = {};
                z = __builtin_amdgcn_mfma_f32_16x16x32_bf16(ka, qf0, z, 0, 0, 0);
                st[s] = __builtin_amdgcn_mfma_f32_16x16x32_bf16(kb2, qf1, z, 0, 0, 0);
            }

            // V^T frags (consumed after softmax; ds latency hides under it)
            bf16x8 vf[4][2];
#pragma unroll
            for (int d = 0; d < 4; ++d) {
                const int rb = (d * 16 + l15) * 64;
                vf[d][0] = *(const bf16x8*)&v_lds[rb + ((lg * 8) ^ xork)];
                vf[d][1] = *(const bf16x8*)&v_lds[rb + ((32 + lg * 8) ^ xork)];
            }

            float sv[16];
#pragma unroll
            for (int s = 0; s < 4; ++s)
#pragma unroll
                for (int j = 0; j < 4; ++j) sv[s * 4 + j] = st[s][j] * SC;

            if (kv0 + 63 > qrow0) {  // wave-uniform: only the diagonal tile masks
#pragma unroll
                for (int s = 0; s < 4; ++s)
#pragma unroll
                    for (int j = 0; j < 4; ++j)
                        if (kv0 + s * 16 + 4 * lg + j > qg) sv[s * 4 + j] = -1e30f;
            }

            float tm = sv[0];
#pragma unroll
            for (int r = 1; r < 16; ++r) tm = fmaxf(tm, sv[r]);
            tm = fmaxf(tm, __shfl_xor(tm, 16, 64));
            tm = fmaxf(tm, __shfl_xor(tm, 32, 64));

            const float newm = fmaxf(m, tm);
            const float al = exp2f(m - newm);
            m = newm;
            float ps[16], ts = 0.f;
#pragma unroll
            for (int r = 0; r < 16; ++r) {
                ps[r] = exp2f(sv[r] - newm);
                ts += ps[r];
            }
            ts += __shfl_xor(ts, 16, 64);
            ts += __shfl_xor(ts, 32, 64);
            lsum = lsum * al + ts;
#pragma unroll
            for (int d = 0; d < 4; ++d)
#pragma unroll
                for (int j = 0; j < 4; ++j) acc[d][j] *= al;

            // two register butterflies: ps[0..7] -> pf0 (kv 0-31), ps[8..15] -> pf1
            bf16x8 pf[2];
#pragma unroll
            for (int hh = 0; hh < 2; ++hh) {
                const float* p8 = &ps[hh * 8];
                unsigned wsp[2][2];
#pragma unroll
                for (int s = 0; s < 2; ++s)
#pragma unroll
                    for (int p2 = 0; p2 < 2; ++p2)
                        wsp[s][p2] = (unsigned)f2bf(p8[s * 4 + 2 * p2]) |
                                     ((unsigned)f2bf(p8[s * 4 + 2 * p2 + 1]) << 16);
                unsigned n0[2], n1[2];
#pragma unroll
                for (int p2 = 0; p2 < 2; ++p2) {
                    unsigned snd = c5 ? wsp[0][p2] : wsp[1][p2];
                    unsigned exch = __shfl_xor((int)snd, 32, 64);
                    n0[p2] = c5 ? exch : wsp[0][p2];
                    n1[p2] = c5 ? wsp[1][p2] : exch;
                }
                unsigned f0[2], f1[2];
#pragma unroll
                for (int p2 = 0; p2 < 2; ++p2) {
                    unsigned snd = c4 ? n0[p2] : n1[p2];
                    unsigned exch = __shfl_xor((int)snd, 16, 64);
                    f0[p2] = c4 ? exch : n0[p2];
                    f1[p2] = c4 ? n1[p2] : exch;
                }
                union { unsigned u[4]; bf16x8 v; } pu;
                pu.u[0] = f0[0]; pu.u[1] = f0[1]; pu.u[2] = f1[0]; pu.u[3] = f1[1];
                pf[hh] = pu.v;
            }

            // PV: O^T = V^T . P^T  (two 32-kv chunks)
#pragma unroll
            for (int d = 0; d < 4; ++d) {
                acc[d] = __builtin_amdgcn_mfma_f32_16x16x32_bf16(vf[d][0], pf[0], acc[d], 0, 0, 0);
                acc[d] = __builtin_amdgcn_mfma_f32_16x16x32_bf16(vf[d][1], pf[1], acc[d], 0, 0, 0);
            }
        }

        const float inv = 1.0f / lsum;
#pragma unroll
        for (int d = 0; d < 4; ++d) {
            ushort4 o;
            o.x = f2bf(acc[d][0] * inv);
            o.y = f2bf(acc[d][1] * inv);
            o.z = f2bf(acc[d][2] * inv);
            o.w = f2bf(acc[d][3] * inv);
            *(ushort4*)&X[(size_t)(b * SEQ + qg) * DM + h * DK + d * 16 + 4 * lg] = o;
        }
    }
}

extern "C" void kernel_launch(void* const* d_in, const int* in_sizes, int n_in,
                              void* d_out, int out_size, void* d_ws, size_t ws_size,
                              hipStream_t stream) {
    const float* q  = (const float*)d_in[0];
    const float* k  = (const float*)d_in[1];
    const float* v  = (const float*)d_in[2];
    const float* Wq = (const float*)d_in[4];
    const float* bq = (const float*)d_in[5];
    const float* Wk = (const float*)d_in[6];
    const float* bk = (const float*)d_in[7];
    const float* Wv = (const float*)d_in[8];
    const float* bv = (const float*)d_in[9];
    const float* Wo = (const float*)d_in[10];
    const float* bo = (const float*)d_in[11];

    const size_t NEL = (size_t)4 * SEQ * DM;  // 8,388,608 elems per buffer
    const size_t WEL = (size_t)DM * DM;       // 1,048,576 elems per weight
    unsigned short* Qp  = (unsigned short*)d_ws;
    unsigned short* Kp  = Qp + NEL;
    unsigned short* Vp  = Kp + NEL;
    unsigned short* Vt  = Vp + NEL;
    unsigned short* Wob = Vt + NEL;   // ws total: 4*NEL + WEL ushorts (~69 MB)
    unsigned short* Xp  = Vp;         // reuse V's slot after transpose
    // Wq/Wk/Wv bf16 live in d_out scratch (overwritten by the final GEMM)
    unsigned short* Wqb = (unsigned short*)d_out;
    unsigned short* Wkb = Wqb + WEL;
    unsigned short* Wvb = Wkb + WEL;

    dim3 gg(64, 8), gb(256);
    hipLaunchKernelGGL(cvt_w, dim3(1024, 4), gb, 0, stream, Wq, Wk, Wv, Wo, Wqb, Wkb, Wvb, Wob);
    hipLaunchKernelGGL((gemm_bt<false, true, false>), gg, gb, 0, stream, (const void*)q, (const void*)Wqb, bq, (void*)Qp, 8192, DM, DM);
    hipLaunchKernelGGL((gemm_bt<false, true, false>), gg, gb, 0, stream, (const void*)k, (const void*)Wkb, bk, (void*)Kp, 8192, DM, DM);
    hipLaunchKernelGGL((gemm_bt<false, true, false>), gg, gb, 0, stream, (const void*)v, (const void*)Wvb, bv, (void*)Vp, 8192, DM, DM);
    hipLaunchKernelGGL(transpose_v, dim3(32, 64), gb, 0, stream, Vp, Vt);
    hipLaunchKernelGGL(attn, dim3(1024), gb, 0, stream, Qp, Kp, Vt, Xp);
    hipLaunchKernelGGL((gemm_bt<true, true, true>), gg, gb, 0, stream, (const void*)Xp, (const void*)Wob, bo, d_out, 8192, DM, DM);
}

// Round 8
// 269.032 us; speedup vs baseline: 2.5041x; 1.0394x over previous
//
#include <hip/hip_runtime.h>

#define DM 1024
#define SEQ 2048
#define NH 16
#define DK 64

typedef __bf16 bf16x8 __attribute__((ext_vector_type(8)));
typedef float f32x4 __attribute__((ext_vector_type(4)));

__device__ inline unsigned short f2bf(float f) {
    unsigned u = __float_as_uint(f);
    u += 0x7fffu + ((u >> 16) & 1u);
    return (unsigned short)(u >> 16);
}

// packed bf16 pair via native casts (compiler emits v_cvt_pk_bf16_f32)
__device__ inline unsigned pkbf(float lo, float hi) {
    union { __bf16 h[2]; unsigned u; } r;
    r.h[0] = (__bf16)lo; r.h[1] = (__bf16)hi;
    return r.u;
}

// fp32 -> bf16 for the four weight matrices (1M elems each), one dispatch.
__global__ __launch_bounds__(256) void cvt_w(const float* __restrict__ s0,
                                             const float* __restrict__ s1,
                                             const float* __restrict__ s2,
                                             const float* __restrict__ s3,
                                             unsigned short* __restrict__ d0,
                                             unsigned short* __restrict__ d1,
                                             unsigned short* __restrict__ d2,
                                             unsigned short* __restrict__ d3) {
    const float* s;
    unsigned short* d;
    switch (blockIdx.y) {
        case 0: s = s0; d = d0; break;
        case 1: s = s1; d = d1; break;
        case 2: s = s2; d = d2; break;
        default: s = s3; d = d3; break;
    }
    int i = (blockIdx.x * 256 + threadIdx.x) * 4;
    float4 v = *(const float4*)(s + i);
    ushort4 o;
    o.x = f2bf(v.x); o.y = f2bf(v.y); o.z = f2bf(v.z); o.w = f2bf(v.w);
    *(ushort4*)(d + i) = o;
}

// C[M,N] = A[M,K] @ W[N,K]^T + bias[N].  W is bf16 (pre-converted).
// m97-style: BK=64, LDS [128][64] bf16 LINEAR, T2 slot-swizzle (slot^=(row&7)).
// W staged via global_load_lds w/ pre-swizzled per-lane SOURCE (LDS dest linear);
// A reg-staged w/ fused fp32->bf16 cvt (A_BF16=false) or gload_lds (true).
template <bool A_BF16, bool OUT_F32>
__global__ __launch_bounds__(256) void gemm_bt(const void* __restrict__ Av,
                                               const unsigned short* __restrict__ W,
                                               const float* __restrict__ bias,
                                               void* __restrict__ Cv,
                                               int M, int N, int K) {
    __shared__ unsigned short lds_a[128 * 64];
    __shared__ unsigned short lds_w[128 * 64];

    const int t = threadIdx.x;
    const int lane = t & 63;
    const int w = t >> 6;
    const int wr = w >> 1, wc = w & 1;
    const int rowBase = blockIdx.x * 128;
    const int colBase = blockIdx.y * 128;
    const int l15 = lane & 15;
    const int lg = lane >> 4;
    const int ar = t >> 1, ah = t & 1;  // A reg-path: row, col-half (32 elems)

    f32x4 acc[4][4] = {};

    for (int k0 = 0; k0 < K; k0 += 64) {
        // ---- stage W: 4 x global_load_lds(16B), source col pre-swizzled ----
#pragma unroll
        for (int i = 0; i < 4; ++i) {
            const int row = (w * 4 + i) * 8 + (lane >> 3);
            const int sl = lane & 7;
            const unsigned short* src =
                W + (size_t)(colBase + row) * K + k0 + ((sl ^ (row & 7)) * 8);
            __builtin_amdgcn_global_load_lds(src, &lds_w[(w * 4 + i) * 512], 16, 0, 0);
        }
        // ---- stage A ----
        if (A_BF16) {
#pragma unroll
            for (int i = 0; i < 4; ++i) {
                const int row = (w * 4 + i) * 8 + (lane >> 3);
                const int sl = lane & 7;
                const unsigned short* src = (const unsigned short*)Av +
                    (size_t)(rowBase + row) * K + k0 + ((sl ^ (row & 7)) * 8);
                __builtin_amdgcn_global_load_lds(src, &lds_a[(w * 4 + i) * 512], 16, 0, 0);
            }
        } else {
            const float* Af = (const float*)Av + (size_t)(rowBase + ar) * K + k0 + ah * 32;
#pragma unroll
            for (int i = 0; i < 4; ++i) {
                float4 f0 = *(const float4*)(Af + i * 8);
                float4 f1 = *(const float4*)(Af + i * 8 + 4);
                union { __bf16 h[8]; uint4 u; } pk;
                pk.h[0] = (__bf16)f0.x; pk.h[1] = (__bf16)f0.y;
                pk.h[2] = (__bf16)f0.z; pk.h[3] = (__bf16)f0.w;
                pk.h[4] = (__bf16)f1.x; pk.h[5] = (__bf16)f1.y;
                pk.h[6] = (__bf16)f1.z; pk.h[7] = (__bf16)f1.w;
                *(uint4*)&lds_a[ar * 64 + (((ah * 4 + i) ^ (ar & 7)) * 8)] = pk.u;
            }
        }
        __syncthreads();  // drains vmcnt (gload_lds) + lgkmcnt (ds_write)

#pragma unroll
        for (int kh = 0; kh < 2; ++kh) {
            bf16x8 af[4], wf[4];
#pragma unroll
            for (int m = 0; m < 4; ++m)
                af[m] = *(const bf16x8*)&lds_a[(wr * 64 + m * 16 + l15) * 64 +
                                               (((kh * 4 + lg) ^ (l15 & 7)) * 8)];
#pragma unroll
            for (int n = 0; n < 4; ++n)
                wf[n] = *(const bf16x8*)&lds_w[(wc * 64 + n * 16 + l15) * 64 +
                                               (((kh * 4 + lg) ^ (l15 & 7)) * 8)];
#pragma unroll
            for (int m = 0; m < 4; ++m)
#pragma unroll
                for (int n = 0; n < 4; ++n)
                    acc[m][n] = __builtin_amdgcn_mfma_f32_16x16x32_bf16(af[m], wf[n],
                                                                        acc[m][n], 0, 0, 0);
        }
        __syncthreads();
    }

#pragma unroll
    for (int m = 0; m < 4; ++m) {
        int row = rowBase + wr * 64 + m * 16 + lg * 4;
#pragma unroll
        for (int n = 0; n < 4; ++n) {
            int col = colBase + wc * 64 + n * 16 + l15;
            float bv = bias[col];
#pragma unroll
            for (int j = 0; j < 4; ++j) {
                float val = acc[m][n][j] + bv;
                if (OUT_F32)
                    ((float*)Cv)[(size_t)(row + j) * N + col] = val;
                else
                    ((unsigned short*)Cv)[(size_t)(row + j) * N + col] = f2bf(val);
            }
        }
    }
}

// V [B,S, H*64] bf16  ->  Vt [B*H, 64, S] bf16
__global__ __launch_bounds__(256) void transpose_v(const unsigned short* __restrict__ V,
                                                   unsigned short* __restrict__ Vt) {
    __shared__ unsigned short tile[64][65];
    int s0 = blockIdx.x * 64;
    int bh = blockIdx.y;
    int b = bh >> 4, h = bh & 15;
    int t = threadIdx.x;
#pragma unroll
    for (int i = 0; i < 8; ++i) {
        int slot = t + 256 * i;
        int s = slot >> 5;
        int d2 = (slot & 31) * 2;
        const unsigned short* src = V + (size_t)(b * SEQ + s0 + s) * DM + h * DK + d2;
        ushort2 v = *(const ushort2*)src;
        tile[s][d2] = v.x;
        tile[s][d2 + 1] = v.y;
    }
    __syncthreads();
#pragma unroll
    for (int i = 0; i < 8; ++i) {
        int slot = t + 256 * i;
        int d = slot >> 5;
        int s2 = (slot & 31) * 2;
        ushort2 v;
        v.x = tile[s2][d];
        v.y = tile[s2 + 1][d];
        unsigned short* dst = Vt + (size_t)(bh * DK + d) * SEQ + s0 + s2;
        *(ushort2*)dst = v;
    }
}

// Flash attention, causal, swapped-operand, LDS-staged K/V (shared by 4 waves).
// + native-cast P packing (v_cvt_pk_bf16_f32) and T13 defer-max.
__global__ __launch_bounds__(256) void attn(const unsigned short* __restrict__ Q,
                                            const unsigned short* __restrict__ K,
                                            const unsigned short* __restrict__ Vt,
                                            unsigned short* __restrict__ X) {
    __shared__ unsigned short k_lds[64 * 64];  // [kv][d], swizzled
    __shared__ unsigned short v_lds[64 * 64];  // [d][kv] (V^T rows), swizzled

    const int t = threadIdx.x;
    const int lane = t & 63;
    const int w = t >> 6;
    const int l15 = lane & 15, lg = lane >> 4;
    const int c4 = (lane >> 4) & 1, c5 = (lane >> 5) & 1;

    const int orig = blockIdx.x;
    const int flat = (orig & 7) * 128 + (orig >> 3);
    const int bh = flat >> 4;
    const int pr = flat & 15;  // pair id 0..15
    const int b = bh >> 4, h = bh & 15;

    const unsigned short* Qb = Q + (size_t)b * SEQ * DM + h * DK;
    const unsigned short* Kb = K + (size_t)b * SEQ * DM + h * DK;
    const unsigned short* Vb = Vt + (size_t)bh * DK * SEQ;
    const float SC = 0.125f * 1.44269504f;  // /sqrt(64) * log2(e)

    const int sr = t >> 3;            // staging row 0..31
    const int sc8 = (t & 7) * 8;      // staging col
    const int sxo = (sr & 7) * 8;     // write swizzle
    const int xork = (l15 & 7) * 8;   // read swizzle

    bf16x8 kr0, kr1, vr0, vr1;

    for (int task = 0; task < 2; ++task) {
        const int qt = task ? 31 - pr : pr;
        const int q0 = qt * 64;
        const int qrow0 = q0 + w * 16;
        const int qg = qrow0 + l15;

        const bf16x8 qf0 = *(const bf16x8*)(Qb + (size_t)(qrow0 + l15) * DM + lg * 8);
        const bf16x8 qf1 = *(const bf16x8*)(Qb + (size_t)(qrow0 + l15) * DM + lg * 8 + 32);

        f32x4 acc[4] = {};
        float m = -1e30f, lsum = 0.f;
        const int nt = qt + 1;

        {
            kr0 = *(const bf16x8*)(Kb + (size_t)sr * DM + sc8);
            kr1 = *(const bf16x8*)(Kb + (size_t)(32 + sr) * DM + sc8);
            vr0 = *(const bf16x8*)(Vb + (size_t)sr * SEQ + sc8);
            vr1 = *(const bf16x8*)(Vb + (size_t)(32 + sr) * SEQ + sc8);
        }

        for (int tile = 0; tile < nt; ++tile) {
            const int kv0 = tile << 6;
            __syncthreads();
            *(bf16x8*)&k_lds[sr * 64 + (sc8 ^ sxo)] = kr0;
            *(bf16x8*)&k_lds[(sr + 32) * 64 + (sc8 ^ sxo)] = kr1;
            *(bf16x8*)&v_lds[sr * 64 + (sc8 ^ sxo)] = vr0;
            *(bf16x8*)&v_lds[(sr + 32) * 64 + (sc8 ^ sxo)] = vr1;
            __syncthreads();

            if (tile + 1 < nt) {
                const int kn = (tile + 1) << 6;
                kr0 = *(const bf16x8*)(Kb + (size_t)(kn + sr) * DM + sc8);
                kr1 = *(const bf16x8*)(Kb + (size_t)(kn + 32 + sr) * DM + sc8);
                vr0 = *(const bf16x8*)(Vb + (size_t)sr * SEQ + kn + sc8);
                vr1 = *(const bf16x8*)(Vb + (size_t)(32 + sr) * SEQ + kn + sc8);
            }

            f32x4 st[4];
#pragma unroll
            for (int s = 0; s < 4; ++s) {
                const int rb = (s * 16 + l15) * 64;
                bf16x8 ka = *(const bf16x8*)&k_lds[rb + ((lg * 8) ^ xork)];
                bf16x8 kb2 = *(const bf16x8*)&k_lds[rb + ((32 + lg * 8) ^ xork)];
                f32x4 z = {};
                z = __builtin_amdgcn_mfma_f32_16x16x32_bf16(ka, qf0, z, 0, 0, 0);
                st[s] = __builtin_amdgcn_mfma_f32_16x16x32_bf16(kb2, qf1, z, 0, 0, 0);
            }

            bf16x8 vf[4][2];
#pragma unroll
            for (int d = 0; d < 4; ++d) {
                const int rb = (d * 16 + l15) * 64;
                vf[d][0] = *(const bf16x8*)&v_lds[rb + ((lg * 8) ^ xork)];
                vf[d][1] = *(const bf16x8*)&v_lds[rb + ((32 + lg * 8) ^ xork)];
            }

            float sv[16];
#pragma unroll
            for (int s = 0; s < 4; ++s)
#pragma unroll
                for (int j = 0; j < 4; ++j) sv[s * 4 + j] = st[s][j] * SC;

            if (kv0 + 63 > qrow0) {
#pragma unroll
                for (int s = 0; s < 4; ++s)
#pragma unroll
                    for (int j = 0; j < 4; ++j)
                        if (kv0 + s * 16 + 4 * lg + j > qg) sv[s * 4 + j] = -1e30f;
            }

            float tm = sv[0];
#pragma unroll
            for (int r = 1; r < 16; ++r) tm = fmaxf(tm, sv[r]);
            tm = fmaxf(tm, __shfl_xor(tm, 16, 64));
            tm = fmaxf(tm, __shfl_xor(tm, 32, 64));

            // T13 defer-max: skip rescale while max growth <= 8 (P <= 2^8)
            if (!__all(tm <= m + 8.0f)) {
                const float newm = fmaxf(m, tm);
                const float al = exp2f(m - newm);
                m = newm;
                lsum *= al;
#pragma unroll
                for (int d = 0; d < 4; ++d)
#pragma unroll
                    for (int j = 0; j < 4; ++j) acc[d][j] *= al;
            }

            float ps[16], ts = 0.f;
#pragma unroll
            for (int r = 0; r < 16; ++r) {
                ps[r] = exp2f(sv[r] - m);
                ts += ps[r];
            }
            ts += __shfl_xor(ts, 16, 64);
            ts += __shfl_xor(ts, 32, 64);
            lsum += ts;

            bf16x8 pf[2];
#pragma unroll
            for (int hh = 0; hh < 2; ++hh) {
                const float* p8 = &ps[hh * 8];
                unsigned wsp[2][2];
#pragma unroll
                for (int s = 0; s < 2; ++s)
#pragma unroll
                    for (int p2 = 0; p2 < 2; ++p2)
                        wsp[s][p2] = pkbf(p8[s * 4 + 2 * p2], p8[s * 4 + 2 * p2 + 1]);
                unsigned n0[2], n1[2];
#pragma unroll
                for (int p2 = 0; p2 < 2; ++p2) {
                    unsigned snd = c5 ? wsp[0][p2] : wsp[1][p2];
                    unsigned exch = __shfl_xor((int)snd, 32, 64);
                    n0[p2] = c5 ? exch : wsp[0][p2];
                    n1[p2] = c5 ? wsp[1][p2] : exch;
                }
                unsigned f0[2], f1[2];
#pragma unroll
                for (int p2 = 0; p2 < 2; ++p2) {
                    unsigned snd = c4 ? n0[p2] : n1[p2];
                    unsigned exch = __shfl_xor((int)snd, 16, 64);
                    f0[p2] = c4 ? exch : n0[p2];
                    f1[p2] = c4 ? n1[p2] : exch;
                }
                union { unsigned u[4]; bf16x8 v; } pu;
                pu.u[0] = f0[0]; pu.u[1] = f0[1]; pu.u[2] = f1[0]; pu.u[3] = f1[1];
                pf[hh] = pu.v;
            }

#pragma unroll
            for (int d = 0; d < 4; ++d) {
                acc[d] = __builtin_amdgcn_mfma_f32_16x16x32_bf16(vf[d][0], pf[0], acc[d], 0, 0, 0);
                acc[d] = __builtin_amdgcn_mfma_f32_16x16x32_bf16(vf[d][1], pf[1], acc[d], 0, 0, 0);
            }
        }

        const float inv = 1.0f / lsum;
#pragma unroll
        for (int d = 0; d < 4; ++d) {
            ushort4 o;
            o.x = f2bf(acc[d][0] * inv);
            o.y = f2bf(acc[d][1] * inv);
            o.z = f2bf(acc[d][2] * inv);
            o.w = f2bf(acc[d][3] * inv);
            *(ushort4*)&X[(size_t)(b * SEQ + qg) * DM + h * DK + d * 16 + 4 * lg] = o;
        }
    }
}

extern "C" void kernel_launch(void* const* d_in, const int* in_sizes, int n_in,
                              void* d_out, int out_size, void* d_ws, size_t ws_size,
                              hipStream_t stream) {
    const float* q  = (const float*)d_in[0];
    const float* k  = (const float*)d_in[1];
    const float* v  = (const float*)d_in[2];
    const float* Wq = (const float*)d_in[4];
    const float* bq = (const float*)d_in[5];
    const float* Wk = (const float*)d_in[6];
    const float* bk = (const float*)d_in[7];
    const float* Wv = (const float*)d_in[8];
    const float* bv = (const float*)d_in[9];
    const float* Wo = (const float*)d_in[10];
    const float* bo = (const float*)d_in[11];

    const size_t NEL = (size_t)4 * SEQ * DM;  // 8,388,608 elems per buffer
    const size_t WEL = (size_t)DM * DM;       // 1,048,576 elems per weight
    unsigned short* Qp  = (unsigned short*)d_ws;
    unsigned short* Kp  = Qp + NEL;
    unsigned short* Vp  = Kp + NEL;
    unsigned short* Vt  = Vp + NEL;
    unsigned short* Wob = Vt + NEL;
    unsigned short* Xp  = Vp;  // reuse V's slot after transpose
    unsigned short* Wqb = (unsigned short*)d_out;  // d_out as scratch until final GEMM
    unsigned short* Wkb = Wqb + WEL;
    unsigned short* Wvb = Wkb + WEL;

    dim3 gg(64, 8), gb(256);
    hipLaunchKernelGGL(cvt_w, dim3(1024, 4), gb, 0, stream, Wq, Wk, Wv, Wo, Wqb, Wkb, Wvb, Wob);
    hipLaunchKernelGGL((gemm_bt<false, false>), gg, gb, 0, stream, (const void*)q, Wqb, bq, (void*)Qp, 8192, DM, DM);
    hipLaunchKernelGGL((gemm_bt<false, false>), gg, gb, 0, stream, (const void*)k, Wkb, bk, (void*)Kp, 8192, DM, DM);
    hipLaunchKernelGGL((gemm_bt<false, false>), gg, gb, 0, stream, (const void*)v, Wvb, bv, (void*)Vp, 8192, DM, DM);
    hipLaunchKernelGGL(transpose_v, dim3(32, 64), gb, 0, stream, Vp, Vt);
    hipLaunchKernelGGL(attn, dim3(1024), gb, 0, stream, Qp, Kp, Vt, Xp);
    hipLaunchKernelGGL((gemm_bt<true, true>), gg, gb, 0, stream, (const void*)Xp, Wob, bo, d_out, 8192, DM, DM);
}

// Round 9
// 263.634 us; speedup vs baseline: 2.5554x; 1.0205x over previous
//
#include <hip/hip_runtime.h>

#define DM 1024
#define SEQ 2048
#define NH 16
#define DK 64

typedef __bf16 bf16x8 __attribute__((ext_vector_type(8)));
typedef float f32x4 __attribute__((ext_vector_type(4)));

__device__ inline unsigned short f2bf(float f) {
    unsigned u = __float_as_uint(f);
    u += 0x7fffu + ((u >> 16) & 1u);
    return (unsigned short)(u >> 16);
}

// packed bf16 pair via native casts (compiler emits v_cvt_pk_bf16_f32)
__device__ inline unsigned pkbf(float lo, float hi) {
    union { __bf16 h[2]; unsigned u; } r;
    r.h[0] = (__bf16)lo; r.h[1] = (__bf16)hi;
    return r.u;
}

// fp32 -> bf16 for the four weight matrices (1M elems each), one dispatch.
__global__ __launch_bounds__(256) void cvt_w(const float* __restrict__ s0,
                                             const float* __restrict__ s1,
                                             const float* __restrict__ s2,
                                             const float* __restrict__ s3,
                                             unsigned short* __restrict__ d0,
                                             unsigned short* __restrict__ d1,
                                             unsigned short* __restrict__ d2,
                                             unsigned short* __restrict__ d3) {
    const float* s;
    unsigned short* d;
    switch (blockIdx.y) {
        case 0: s = s0; d = d0; break;
        case 1: s = s1; d = d1; break;
        case 2: s = s2; d = d2; break;
        default: s = s3; d = d3; break;
    }
    int i = (blockIdx.x * 256 + threadIdx.x) * 4;
    float4 v = *(const float4*)(s + i);
    ushort4 o;
    o.x = f2bf(v.x); o.y = f2bf(v.y); o.z = f2bf(v.z); o.w = f2bf(v.w);
    *(ushort4*)(d + i) = o;
}

// C[M,N] = A[M,K] @ W[N,K]^T + bias[N].  W bf16.  BK=64, dbuf LDS, T2 swizzle.
// 2-phase counted-vmcnt pipeline (T3/T4 minimum recipe): issue tile t+1 loads,
// s_waitcnt vmcnt(N_inflight) + RAW s_barrier (no vmcnt(0) drain), compute t.
// OUT_MODE: 0 = bf16 row-major, 1 = f32 row-major, 2 = bf16 Vt[bh][d][s].
template <bool A_BF16, int OUT_MODE>
__global__ __launch_bounds__(256) void gemm_bt(const void* __restrict__ Av,
                                               const unsigned short* __restrict__ W,
                                               const float* __restrict__ bias,
                                               void* __restrict__ Cv,
                                               int M, int N, int K) {
    __shared__ unsigned short lds_a[2][128 * 64];
    __shared__ unsigned short lds_w[2][128 * 64];

    const int t = threadIdx.x;
    const int lane = t & 63;
    const int w = t >> 6;
    const int wr = w >> 1, wc = w & 1;
    const int rowBase = blockIdx.x * 128;
    const int colBase = blockIdx.y * 128;
    const int l15 = lane & 15;
    const int lg = lane >> 4;
    const int ar = t >> 1, ah = t & 1;  // fp32-A reg path: row, 32-col half
    const int NIT = K >> 6;             // 16

    f32x4 acc[4][4] = {};

    auto STAGE_W = [&](int kt, int buf) {
#pragma unroll
        for (int i = 0; i < 4; ++i) {
            const int row = (w * 4 + i) * 8 + (lane >> 3);
            const int sl = lane & 7;
            const unsigned short* src =
                W + (size_t)(colBase + row) * K + kt * 64 + ((sl ^ (row & 7)) * 8);
            __builtin_amdgcn_global_load_lds(src, &lds_w[buf][(w * 4 + i) * 512], 16, 0, 0);
        }
    };
    auto STAGE_A16 = [&](int kt, int buf) {
#pragma unroll
        for (int i = 0; i < 4; ++i) {
            const int row = (w * 4 + i) * 8 + (lane >> 3);
            const int sl = lane & 7;
            const unsigned short* src = (const unsigned short*)Av +
                (size_t)(rowBase + row) * K + kt * 64 + ((sl ^ (row & 7)) * 8);
            __builtin_amdgcn_global_load_lds(src, &lds_a[buf][(w * 4 + i) * 512], 16, 0, 0);
        }
    };
    auto LOADA = [&](int kt, float4* rf) {
        const float* Af = (const float*)Av + (size_t)(rowBase + ar) * K + kt * 64 + ah * 32;
#pragma unroll
        for (int i = 0; i < 4; ++i) {
            rf[2 * i] = *(const float4*)(Af + i * 8);
            rf[2 * i + 1] = *(const float4*)(Af + i * 8 + 4);
        }
    };
    auto WRITEA = [&](const float4* rf, int buf) {
#pragma unroll
        for (int i = 0; i < 4; ++i) {
            union { __bf16 h[8]; uint4 u; } pk;
            pk.h[0] = (__bf16)rf[2 * i].x; pk.h[1] = (__bf16)rf[2 * i].y;
            pk.h[2] = (__bf16)rf[2 * i].z; pk.h[3] = (__bf16)rf[2 * i].w;
            pk.h[4] = (__bf16)rf[2 * i + 1].x; pk.h[5] = (__bf16)rf[2 * i + 1].y;
            pk.h[6] = (__bf16)rf[2 * i + 1].z; pk.h[7] = (__bf16)rf[2 * i + 1].w;
            *(uint4*)&lds_a[buf][ar * 64 + (((ah * 4 + i) ^ (ar & 7)) * 8)] = pk.u;
        }
    };
    auto COMPUTE = [&](int buf) {
#pragma unroll
        for (int kh = 0; kh < 2; ++kh) {
            bf16x8 af[4], wf[4];
#pragma unroll
            for (int m = 0; m < 4; ++m)
                af[m] = *(const bf16x8*)&lds_a[buf][(wr * 64 + m * 16 + l15) * 64 +
                                                   (((kh * 4 + lg) ^ (l15 & 7)) * 8)];
#pragma unroll
            for (int n = 0; n < 4; ++n)
                wf[n] = *(const bf16x8*)&lds_w[buf][(wc * 64 + n * 16 + l15) * 64 +
                                                   (((kh * 4 + lg) ^ (l15 & 7)) * 8)];
#pragma unroll
            for (int m = 0; m < 4; ++m)
#pragma unroll
                for (int n = 0; n < 4; ++n)
                    acc[m][n] = __builtin_amdgcn_mfma_f32_16x16x32_bf16(af[m], wf[n],
                                                                        acc[m][n], 0, 0, 0);
        }
    };

    if (A_BF16) {
        STAGE_W(0, 0);
        STAGE_A16(0, 0);
        for (int kt = 0; kt < NIT; ++kt) {
            const int cur = kt & 1;
            if (kt + 1 < NIT) {
                STAGE_W(kt + 1, cur ^ 1);
                STAGE_A16(kt + 1, cur ^ 1);
                asm volatile("s_waitcnt vmcnt(8)" ::: "memory");
            } else {
                asm volatile("s_waitcnt vmcnt(0)" ::: "memory");
            }
            __builtin_amdgcn_s_barrier();
            COMPUTE(cur);
            __builtin_amdgcn_s_barrier();
        }
    } else {
        float4 ra[8], rb[8];
        STAGE_W(0, 0);
        LOADA(0, ra);
        for (int kt = 0; kt < NIT; kt += 2) {  // NIT even (K=1024)
            if (kt + 1 < NIT) {
                STAGE_W(kt + 1, 1);
                LOADA(kt + 1, rb);
                asm volatile("s_waitcnt vmcnt(12)" ::: "memory");
            } else {
                asm volatile("s_waitcnt vmcnt(0)" ::: "memory");
            }
            WRITEA(ra, 0);
            asm volatile("s_waitcnt lgkmcnt(0)" ::: "memory");
            __builtin_amdgcn_s_barrier();
            COMPUTE(0);
            __builtin_amdgcn_s_barrier();
            if (kt + 2 < NIT) {
                STAGE_W(kt + 2, 0);
                LOADA(kt + 2, ra);
                asm volatile("s_waitcnt vmcnt(12)" ::: "memory");
            } else {
                asm volatile("s_waitcnt vmcnt(0)" ::: "memory");
            }
            WRITEA(rb, 1);
            asm volatile("s_waitcnt lgkmcnt(0)" ::: "memory");
            __builtin_amdgcn_s_barrier();
            COMPUTE(1);
            __builtin_amdgcn_s_barrier();
        }
    }

#pragma unroll
    for (int m = 0; m < 4; ++m) {
        int row = rowBase + wr * 64 + m * 16 + lg * 4;
#pragma unroll
        for (int n = 0; n < 4; ++n) {
            int col = colBase + wc * 64 + n * 16 + l15;
            float bv = bias[col];
            if (OUT_MODE == 2) {
                // Vt[bh][dloc][s]: lane's 4 j-values are 4 consecutive s
                const int bh = (row >> 11) * NH + (col >> 6);
                const int dloc = col & 63;
                const int s = row & (SEQ - 1);
                ushort4 o;
                o.x = f2bf(acc[m][n][0] + bv);
                o.y = f2bf(acc[m][n][1] + bv);
                o.z = f2bf(acc[m][n][2] + bv);
                o.w = f2bf(acc[m][n][3] + bv);
                *(ushort4*)((unsigned short*)Cv + ((size_t)bh * DK + dloc) * SEQ + s) = o;
            } else {
#pragma unroll
                for (int j = 0; j < 4; ++j) {
                    float val = acc[m][n][j] + bv;
                    if (OUT_MODE == 1)
                        ((float*)Cv)[(size_t)(row + j) * N + col] = val;
                    else
                        ((unsigned short*)Cv)[(size_t)(row + j) * N + col] = f2bf(val);
                }
            }
        }
    }
}

// Flash attention, causal, swapped-operand, LDS-staged K/V (shared by 4 waves).
__global__ __launch_bounds__(256) void attn(const unsigned short* __restrict__ Q,
                                            const unsigned short* __restrict__ K,
                                            const unsigned short* __restrict__ Vt,
                                            unsigned short* __restrict__ X) {
    __shared__ unsigned short k_lds[64 * 64];  // [kv][d], swizzled
    __shared__ unsigned short v_lds[64 * 64];  // [d][kv] (V^T rows), swizzled

    const int t = threadIdx.x;
    const int lane = t & 63;
    const int w = t >> 6;
    const int l15 = lane & 15, lg = lane >> 4;
    const int c4 = (lane >> 4) & 1, c5 = (lane >> 5) & 1;

    const int orig = blockIdx.x;
    const int flat = (orig & 7) * 128 + (orig >> 3);
    const int bh = flat >> 4;
    const int pr = flat & 15;  // pair id 0..15
    const int b = bh >> 4, h = bh & 15;

    const unsigned short* Qb = Q + (size_t)b * SEQ * DM + h * DK;
    const unsigned short* Kb = K + (size_t)b * SEQ * DM + h * DK;
    const unsigned short* Vb = Vt + (size_t)bh * DK * SEQ;
    const float SC = 0.125f * 1.44269504f;  // /sqrt(64) * log2(e)

    const int sr = t >> 3;            // staging row 0..31
    const int sc8 = (t & 7) * 8;      // staging col
    const int sxo = (sr & 7) * 8;     // write swizzle
    const int xork = (l15 & 7) * 8;   // read swizzle

    bf16x8 kr0, kr1, vr0, vr1;

    for (int task = 0; task < 2; ++task) {
        const int qt = task ? 31 - pr : pr;
        const int q0 = qt * 64;
        const int qrow0 = q0 + w * 16;
        const int qg = qrow0 + l15;

        const bf16x8 qf0 = *(const bf16x8*)(Qb + (size_t)(qrow0 + l15) * DM + lg * 8);
        const bf16x8 qf1 = *(const bf16x8*)(Qb + (size_t)(qrow0 + l15) * DM + lg * 8 + 32);

        f32x4 acc[4] = {};
        float m = -1e30f, lsum = 0.f;
        const int nt = qt + 1;

        {
            kr0 = *(const bf16x8*)(Kb + (size_t)sr * DM + sc8);
            kr1 = *(const bf16x8*)(Kb + (size_t)(32 + sr) * DM + sc8);
            vr0 = *(const bf16x8*)(Vb + (size_t)sr * SEQ + sc8);
            vr1 = *(const bf16x8*)(Vb + (size_t)(32 + sr) * SEQ + sc8);
        }

        for (int tile = 0; tile < nt; ++tile) {
            const int kv0 = tile << 6;
            __syncthreads();
            *(bf16x8*)&k_lds[sr * 64 + (sc8 ^ sxo)] = kr0;
            *(bf16x8*)&k_lds[(sr + 32) * 64 + (sc8 ^ sxo)] = kr1;
            *(bf16x8*)&v_lds[sr * 64 + (sc8 ^ sxo)] = vr0;
            *(bf16x8*)&v_lds[(sr + 32) * 64 + (sc8 ^ sxo)] = vr1;
            __syncthreads();

            if (tile + 1 < nt) {
                const int kn = (tile + 1) << 6;
                kr0 = *(const bf16x8*)(Kb + (size_t)(kn + sr) * DM + sc8);
                kr1 = *(const bf16x8*)(Kb + (size_t)(kn + 32 + sr) * DM + sc8);
                vr0 = *(const bf16x8*)(Vb + (size_t)sr * SEQ + kn + sc8);
                vr1 = *(const bf16x8*)(Vb + (size_t)(32 + sr) * SEQ + kn + sc8);
            }

            f32x4 st[4];
#pragma unroll
            for (int s = 0; s < 4; ++s) {
                const int rb2 = (s * 16 + l15) * 64;
                bf16x8 ka = *(const bf16x8*)&k_lds[rb2 + ((lg * 8) ^ xork)];
                bf16x8 kb2 = *(const bf16x8*)&k_lds[rb2 + ((32 + lg * 8) ^ xork)];
                f32x4 z = {};
                z = __builtin_amdgcn_mfma_f32_16x16x32_bf16(ka, qf0, z, 0, 0, 0);
                st[s] = __builtin_amdgcn_mfma_f32_16x16x32_bf16(kb2, qf1, z, 0, 0, 0);
            }

            bf16x8 vf[4][2];
#pragma unroll
            for (int d = 0; d < 4; ++d) {
                const int rb2 = (d * 16 + l15) * 64;
                vf[d][0] = *(const bf16x8*)&v_lds[rb2 + ((lg * 8) ^ xork)];
                vf[d][1] = *(const bf16x8*)&v_lds[rb2 + ((32 + lg * 8) ^ xork)];
            }

            float sv[16];
#pragma unroll
            for (int s = 0; s < 4; ++s)
#pragma unroll
                for (int j = 0; j < 4; ++j) sv[s * 4 + j] = st[s][j] * SC;

            if (kv0 + 63 > qrow0) {
#pragma unroll
                for (int s = 0; s < 4; ++s)
#pragma unroll
                    for (int j = 0; j < 4; ++j)
                        if (kv0 + s * 16 + 4 * lg + j > qg) sv[s * 4 + j] = -1e30f;
            }

            float tm = sv[0];
#pragma unroll
            for (int r = 1; r < 16; ++r) tm = fmaxf(tm, sv[r]);
            tm = fmaxf(tm, __shfl_xor(tm, 16, 64));
            tm = fmaxf(tm, __shfl_xor(tm, 32, 64));

            // T13 defer-max: skip rescale while max growth <= 8 (P <= 2^8)
            if (!__all(tm <= m + 8.0f)) {
                const float newm = fmaxf(m, tm);
                const float al = exp2f(m - newm);
                m = newm;
                lsum *= al;
#pragma unroll
                for (int d = 0; d < 4; ++d)
#pragma unroll
                    for (int j = 0; j < 4; ++j) acc[d][j] *= al;
            }

            float ps[16], ts = 0.f;
#pragma unroll
            for (int r = 0; r < 16; ++r) {
                ps[r] = exp2f(sv[r] - m);
                ts += ps[r];
            }
            ts += __shfl_xor(ts, 16, 64);
            ts += __shfl_xor(ts, 32, 64);
            lsum += ts;

            bf16x8 pf[2];
#pragma unroll
            for (int hh = 0; hh < 2; ++hh) {
                const float* p8 = &ps[hh * 8];
                unsigned wsp[2][2];
#pragma unroll
                for (int s = 0; s < 2; ++s)
#pragma unroll
                    for (int p2 = 0; p2 < 2; ++p2)
                        wsp[s][p2] = pkbf(p8[s * 4 + 2 * p2], p8[s * 4 + 2 * p2 + 1]);
                unsigned n0[2], n1[2];
#pragma unroll
                for (int p2 = 0; p2 < 2; ++p2) {
                    unsigned snd = c5 ? wsp[0][p2] : wsp[1][p2];
                    unsigned exch = __shfl_xor((int)snd, 32, 64);
                    n0[p2] = c5 ? exch : wsp[0][p2];
                    n1[p2] = c5 ? wsp[1][p2] : exch;
                }
                unsigned f0[2], f1[2];
#pragma unroll
                for (int p2 = 0; p2 < 2; ++p2) {
                    unsigned snd = c4 ? n0[p2] : n1[p2];
                    unsigned exch = __shfl_xor((int)snd, 16, 64);
                    f0[p2] = c4 ? exch : n0[p2];
                    f1[p2] = c4 ? n1[p2] : exch;
                }
                union { unsigned u[4]; bf16x8 v; } pu;
                pu.u[0] = f0[0]; pu.u[1] = f0[1]; pu.u[2] = f1[0]; pu.u[3] = f1[1];
                pf[hh] = pu.v;
            }

#pragma unroll
            for (int d = 0; d < 4; ++d) {
                acc[d] = __builtin_amdgcn_mfma_f32_16x16x32_bf16(vf[d][0], pf[0], acc[d], 0, 0, 0);
                acc[d] = __builtin_amdgcn_mfma_f32_16x16x32_bf16(vf[d][1], pf[1], acc[d], 0, 0, 0);
            }
        }

        const float inv = 1.0f / lsum;
#pragma unroll
        for (int d = 0; d < 4; ++d) {
            ushort4 o;
            o.x = f2bf(acc[d][0] * inv);
            o.y = f2bf(acc[d][1] * inv);
            o.z = f2bf(acc[d][2] * inv);
            o.w = f2bf(acc[d][3] * inv);
            *(ushort4*)&X[(size_t)(b * SEQ + qg) * DM + h * DK + d * 16 + 4 * lg] = o;
        }
    }
}

extern "C" void kernel_launch(void* const* d_in, const int* in_sizes, int n_in,
                              void* d_out, int out_size, void* d_ws, size_t ws_size,
                              hipStream_t stream) {
    const float* q  = (const float*)d_in[0];
    const float* k  = (const float*)d_in[1];
    const float* v  = (const float*)d_in[2];
    const float* Wq = (const float*)d_in[4];
    const float* bq = (const float*)d_in[5];
    const float* Wk = (const float*)d_in[6];
    const float* bk = (const float*)d_in[7];
    const float* Wv = (const float*)d_in[8];
    const float* bv = (const float*)d_in[9];
    const float* Wo = (const float*)d_in[10];
    const float* bo = (const float*)d_in[11];

    const size_t NEL = (size_t)4 * SEQ * DM;  // 8,388,608 elems per buffer
    const size_t WEL = (size_t)DM * DM;       // 1,048,576 elems per weight
    unsigned short* Qp  = (unsigned short*)d_ws;
    unsigned short* Kp  = Qp + NEL;
    unsigned short* Vp  = Kp + NEL;   // now only used for attn output Xp
    unsigned short* Vt  = Vp + NEL;
    unsigned short* Wob = Vt + NEL;
    unsigned short* Xp  = Vp;
    unsigned short* Wqb = (unsigned short*)d_out;  // d_out as scratch until final GEMM
    unsigned short* Wkb = Wqb + WEL;
    unsigned short* Wvb = Wkb + WEL;

    dim3 gg(64, 8), gb(256);
    hipLaunchKernelGGL(cvt_w, dim3(1024, 4), gb, 0, stream, Wq, Wk, Wv, Wo, Wqb, Wkb, Wvb, Wob);
    hipLaunchKernelGGL((gemm_bt<false, 0>), gg, gb, 0, stream, (const void*)q, Wqb, bq, (void*)Qp, 8192, DM, DM);
    hipLaunchKernelGGL((gemm_bt<false, 0>), gg, gb, 0, stream, (const void*)k, Wkb, bk, (void*)Kp, 8192, DM, DM);
    hipLaunchKernelGGL((gemm_bt<false, 2>), gg, gb, 0, stream, (const void*)v, Wvb, bv, (void*)Vt, 8192, DM, DM);
    hipLaunchKernelGGL(attn, dim3(1024), gb, 0, stream, Qp, Kp, Vt, Xp);
    hipLaunchKernelGGL((gemm_bt<true, 1>), gg, gb, 0, stream, (const void*)Xp, Wob, bo, d_out, 8192, DM, DM);
}

// Round 10
// 262.923 us; speedup vs baseline: 2.5623x; 1.0027x over previous
//
#include <hip/hip_runtime.h>

#define DM 1024
#define SEQ 2048
#define NH 16
#define DK 64

typedef __bf16 bf16x8 __attribute__((ext_vector_type(8)));
typedef float f32x4 __attribute__((ext_vector_type(4)));

__device__ inline unsigned short f2bf(float f) {
    unsigned u = __float_as_uint(f);
    u += 0x7fffu + ((u >> 16) & 1u);
    return (unsigned short)(u >> 16);
}

// packed bf16 pair via native casts (compiler emits v_cvt_pk_bf16_f32)
__device__ inline unsigned pkbf(float lo, float hi) {
    union { __bf16 h[2]; unsigned u; } r;
    r.h[0] = (__bf16)lo; r.h[1] = (__bf16)hi;
    return r.u;
}

// fp32 -> bf16 for the four weight matrices (1M elems each), one dispatch.
__global__ __launch_bounds__(256) void cvt_w(const float* __restrict__ s0,
                                             const float* __restrict__ s1,
                                             const float* __restrict__ s2,
                                             const float* __restrict__ s3,
                                             unsigned short* __restrict__ d0,
                                             unsigned short* __restrict__ d1,
                                             unsigned short* __restrict__ d2,
                                             unsigned short* __restrict__ d3) {
    const float* s;
    unsigned short* d;
    switch (blockIdx.y) {
        case 0: s = s0; d = d0; break;
        case 1: s = s1; d = d1; break;
        case 2: s = s2; d = d2; break;
        default: s = s3; d = d3; break;
    }
    int i = (blockIdx.x * 256 + threadIdx.x) * 4;
    float4 v = *(const float4*)(s + i);
    ushort4 o;
    o.x = f2bf(v.x); o.y = f2bf(v.y); o.z = f2bf(v.z); o.w = f2bf(v.w);
    *(ushort4*)(d + i) = o;
}

// C[M,N] = A[M,K] @ W[N,K]^T + bias[N].  W bf16.  BK=64, dbuf LDS, T2 swizzle,
// 2-phase counted-vmcnt pipeline.  Grid: 1D 512 blocks, XCD-chunked 2D swizzle:
// each XCD owns 8 row-panels x 8 col-blocks; consecutive same-XCD blocks sweep
// col-blocks first -> A-panel (512KB) pulled into XCD L2 once, hit 7 times.
// OUT_MODE: 0 = bf16 row-major, 1 = f32 row-major, 2 = bf16 Vt[bh][d][s].
template <bool A_BF16, int OUT_MODE>
__global__ __launch_bounds__(256) void gemm_bt(const void* __restrict__ Av,
                                               const unsigned short* __restrict__ W,
                                               const float* __restrict__ bias,
                                               void* __restrict__ Cv,
                                               int M, int N, int K) {
    __shared__ unsigned short lds_a[2][128 * 64];
    __shared__ unsigned short lds_w[2][128 * 64];

    const int t = threadIdx.x;
    const int lane = t & 63;
    const int w = t >> 6;
    const int wr = w >> 1, wc = w & 1;
    // XCD-chunked swizzle (M=8192 -> 64 row-panels, N=1024 -> 8 col-panels)
    const int bid = blockIdx.x;
    const int xcd = bid & 7;
    const int idx = bid >> 3;
    const int rowBase = (xcd * 8 + (idx >> 3)) * 128;
    const int colBase = (idx & 7) * 128;
    const int l15 = lane & 15;
    const int lg = lane >> 4;
    const int ar = t >> 1, ah = t & 1;  // fp32-A reg path: row, 32-col half
    const int NIT = K >> 6;             // 16

    f32x4 acc[4][4] = {};

    auto STAGE_W = [&](int kt, int buf) {
#pragma unroll
        for (int i = 0; i < 4; ++i) {
            const int row = (w * 4 + i) * 8 + (lane >> 3);
            const int sl = lane & 7;
            const unsigned short* src =
                W + (size_t)(colBase + row) * K + kt * 64 + ((sl ^ (row & 7)) * 8);
            __builtin_amdgcn_global_load_lds(src, &lds_w[buf][(w * 4 + i) * 512], 16, 0, 0);
        }
    };
    auto STAGE_A16 = [&](int kt, int buf) {
#pragma unroll
        for (int i = 0; i < 4; ++i) {
            const int row = (w * 4 + i) * 8 + (lane >> 3);
            const int sl = lane & 7;
            const unsigned short* src = (const unsigned short*)Av +
                (size_t)(rowBase + row) * K + kt * 64 + ((sl ^ (row & 7)) * 8);
            __builtin_amdgcn_global_load_lds(src, &lds_a[buf][(w * 4 + i) * 512], 16, 0, 0);
        }
    };
    auto LOADA = [&](int kt, float4* rf) {
        const float* Af = (const float*)Av + (size_t)(rowBase + ar) * K + kt * 64 + ah * 32;
#pragma unroll
        for (int i = 0; i < 4; ++i) {
            rf[2 * i] = *(const float4*)(Af + i * 8);
            rf[2 * i + 1] = *(const float4*)(Af + i * 8 + 4);
        }
    };
    auto WRITEA = [&](const float4* rf, int buf) {
#pragma unroll
        for (int i = 0; i < 4; ++i) {
            union { __bf16 h[8]; uint4 u; } pk;
            pk.h[0] = (__bf16)rf[2 * i].x; pk.h[1] = (__bf16)rf[2 * i].y;
            pk.h[2] = (__bf16)rf[2 * i].z; pk.h[3] = (__bf16)rf[2 * i].w;
            pk.h[4] = (__bf16)rf[2 * i + 1].x; pk.h[5] = (__bf16)rf[2 * i + 1].y;
            pk.h[6] = (__bf16)rf[2 * i + 1].z; pk.h[7] = (__bf16)rf[2 * i + 1].w;
            *(uint4*)&lds_a[buf][ar * 64 + (((ah * 4 + i) ^ (ar & 7)) * 8)] = pk.u;
        }
    };
    auto COMPUTE = [&](int buf) {
#pragma unroll
        for (int kh = 0; kh < 2; ++kh) {
            bf16x8 af[4], wf[4];
#pragma unroll
            for (int m = 0; m < 4; ++m)
                af[m] = *(const bf16x8*)&lds_a[buf][(wr * 64 + m * 16 + l15) * 64 +
                                                   (((kh * 4 + lg) ^ (l15 & 7)) * 8)];
#pragma unroll
            for (int n = 0; n < 4; ++n)
                wf[n] = *(const bf16x8*)&lds_w[buf][(wc * 64 + n * 16 + l15) * 64 +
                                                   (((kh * 4 + lg) ^ (l15 & 7)) * 8)];
#pragma unroll
            for (int m = 0; m < 4; ++m)
#pragma unroll
                for (int n = 0; n < 4; ++n)
                    acc[m][n] = __builtin_amdgcn_mfma_f32_16x16x32_bf16(af[m], wf[n],
                                                                        acc[m][n], 0, 0, 0);
        }
    };

    if (A_BF16) {
        STAGE_W(0, 0);
        STAGE_A16(0, 0);
        for (int kt = 0; kt < NIT; ++kt) {
            const int cur = kt & 1;
            if (kt + 1 < NIT) {
                STAGE_W(kt + 1, cur ^ 1);
                STAGE_A16(kt + 1, cur ^ 1);
                asm volatile("s_waitcnt vmcnt(8)" ::: "memory");
            } else {
                asm volatile("s_waitcnt vmcnt(0)" ::: "memory");
            }
            __builtin_amdgcn_s_barrier();
            COMPUTE(cur);
            __builtin_amdgcn_s_barrier();
        }
    } else {
        float4 ra[8], rb[8];
        STAGE_W(0, 0);
        LOADA(0, ra);
        for (int kt = 0; kt < NIT; kt += 2) {  // NIT even (K=1024)
            if (kt + 1 < NIT) {
                STAGE_W(kt + 1, 1);
                LOADA(kt + 1, rb);
                asm volatile("s_waitcnt vmcnt(12)" ::: "memory");
            } else {
                asm volatile("s_waitcnt vmcnt(0)" ::: "memory");
            }
            WRITEA(ra, 0);
            asm volatile("s_waitcnt lgkmcnt(0)" ::: "memory");
            __builtin_amdgcn_s_barrier();
            COMPUTE(0);
            __builtin_amdgcn_s_barrier();
            if (kt + 2 < NIT) {
                STAGE_W(kt + 2, 0);
                LOADA(kt + 2, ra);
                asm volatile("s_waitcnt vmcnt(12)" ::: "memory");
            } else {
                asm volatile("s_waitcnt vmcnt(0)" ::: "memory");
            }
            WRITEA(rb, 1);
            asm volatile("s_waitcnt lgkmcnt(0)" ::: "memory");
            __builtin_amdgcn_s_barrier();
            COMPUTE(1);
            __builtin_amdgcn_s_barrier();
        }
    }

#pragma unroll
    for (int m = 0; m < 4; ++m) {
        int row = rowBase + wr * 64 + m * 16 + lg * 4;
#pragma unroll
        for (int n = 0; n < 4; ++n) {
            int col = colBase + wc * 64 + n * 16 + l15;
            float bv = bias[col];
            if (OUT_MODE == 2) {
                // Vt[bh][dloc][s]: lane's 4 j-values are 4 consecutive s
                const int bh = (row >> 11) * NH + (col >> 6);
                const int dloc = col & 63;
                const int s = row & (SEQ - 1);
                ushort4 o;
                o.x = f2bf(acc[m][n][0] + bv);
                o.y = f2bf(acc[m][n][1] + bv);
                o.z = f2bf(acc[m][n][2] + bv);
                o.w = f2bf(acc[m][n][3] + bv);
                *(ushort4*)((unsigned short*)Cv + ((size_t)bh * DK + dloc) * SEQ + s) = o;
            } else {
#pragma unroll
                for (int j = 0; j < 4; ++j) {
                    float val = acc[m][n][j] + bv;
                    if (OUT_MODE == 1)
                        ((float*)Cv)[(size_t)(row + j) * N + col] = val;
                    else
                        ((unsigned short*)Cv)[(size_t)(row + j) * N + col] = f2bf(val);
                }
            }
        }
    }
}

// Flash attention, causal, swapped-operand, LDS-staged K/V (shared by 4 waves),
// DOUBLE-BUFFERED: one barrier per kv-step (write buf[gp&1] never conflicts
// with reads of buf[(gp-1)&1]); gp runs across both tasks for parity safety.
__global__ __launch_bounds__(256) void attn(const unsigned short* __restrict__ Q,
                                            const unsigned short* __restrict__ K,
                                            const unsigned short* __restrict__ Vt,
                                            unsigned short* __restrict__ X) {
    __shared__ unsigned short k_lds[2][64 * 64];  // [kv][d], swizzled
    __shared__ unsigned short v_lds[2][64 * 64];  // [d][kv] (V^T rows), swizzled

    const int t = threadIdx.x;
    const int lane = t & 63;
    const int w = t >> 6;
    const int l15 = lane & 15, lg = lane >> 4;
    const int c4 = (lane >> 4) & 1, c5 = (lane >> 5) & 1;

    const int orig = blockIdx.x;
    const int flat = (orig & 7) * 128 + (orig >> 3);
    const int bh = flat >> 4;
    const int pr = flat & 15;  // pair id 0..15
    const int b = bh >> 4, h = bh & 15;

    const unsigned short* Qb = Q + (size_t)b * SEQ * DM + h * DK;
    const unsigned short* Kb = K + (size_t)b * SEQ * DM + h * DK;
    const unsigned short* Vb = Vt + (size_t)bh * DK * SEQ;
    const float SC = 0.125f * 1.44269504f;  // /sqrt(64) * log2(e)

    const int sr = t >> 3;            // staging row 0..31
    const int sc8 = (t & 7) * 8;      // staging col
    const int sxo = (sr & 7) * 8;     // write swizzle
    const int xork = (l15 & 7) * 8;   // read swizzle

    bf16x8 kr0, kr1, vr0, vr1;
    int gp = 0;

    auto LOADT = [&](int kv0) {
        kr0 = *(const bf16x8*)(Kb + (size_t)(kv0 + sr) * DM + sc8);
        kr1 = *(const bf16x8*)(Kb + (size_t)(kv0 + 32 + sr) * DM + sc8);
        vr0 = *(const bf16x8*)(Vb + (size_t)sr * SEQ + kv0 + sc8);
        vr1 = *(const bf16x8*)(Vb + (size_t)(32 + sr) * SEQ + kv0 + sc8);
    };

    LOADT(0);  // task-0 tile-0

    for (int task = 0; task < 2; ++task) {
        const int qt = task ? 31 - pr : pr;
        const int qrow0 = qt * 64 + w * 16;
        const int qg = qrow0 + l15;

        const bf16x8 qf0 = *(const bf16x8*)(Qb + (size_t)(qrow0 + l15) * DM + lg * 8);
        const bf16x8 qf1 = *(const bf16x8*)(Qb + (size_t)(qrow0 + l15) * DM + lg * 8 + 32);

        f32x4 acc[4] = {};
        float m = -1e30f, lsum = 0.f;
        const int nt = qt + 1;

        for (int tile = 0; tile < nt; ++tile) {
            const int kv0 = tile << 6;
            unsigned short* kl = k_lds[gp & 1];
            unsigned short* vl = v_lds[gp & 1];
            *(bf16x8*)&kl[sr * 64 + (sc8 ^ sxo)] = kr0;
            *(bf16x8*)&kl[(sr + 32) * 64 + (sc8 ^ sxo)] = kr1;
            *(bf16x8*)&vl[sr * 64 + (sc8 ^ sxo)] = vr0;
            *(bf16x8*)&vl[(sr + 32) * 64 + (sc8 ^ sxo)] = vr1;
            __syncthreads();

            if (tile + 1 < nt)
                LOADT((tile + 1) << 6);
            else if (task == 0)
                LOADT(0);  // prefetch task-1 tile-0

            f32x4 st[4];
#pragma unroll
            for (int s = 0; s < 4; ++s) {
                const int rb2 = (s * 16 + l15) * 64;
                bf16x8 ka = *(const bf16x8*)&kl[rb2 + ((lg * 8) ^ xork)];
                bf16x8 kb2 = *(const bf16x8*)&kl[rb2 + ((32 + lg * 8) ^ xork)];
                f32x4 z = {};
                z = __builtin_amdgcn_mfma_f32_16x16x32_bf16(ka, qf0, z, 0, 0, 0);
                st[s] = __builtin_amdgcn_mfma_f32_16x16x32_bf16(kb2, qf1, z, 0, 0, 0);
            }

            bf16x8 vf[4][2];
#pragma unroll
            for (int d = 0; d < 4; ++d) {
                const int rb2 = (d * 16 + l15) * 64;
                vf[d][0] = *(const bf16x8*)&vl[rb2 + ((lg * 8) ^ xork)];
                vf[d][1] = *(const bf16x8*)&vl[rb2 + ((32 + lg * 8) ^ xork)];
            }

            float sv[16];
#pragma unroll
            for (int s = 0; s < 4; ++s)
#pragma unroll
                for (int j = 0; j < 4; ++j) sv[s * 4 + j] = st[s][j] * SC;

            if (kv0 + 63 > qrow0) {
#pragma unroll
                for (int s = 0; s < 4; ++s)
#pragma unroll
                    for (int j = 0; j < 4; ++j)
                        if (kv0 + s * 16 + 4 * lg + j > qg) sv[s * 4 + j] = -1e30f;
            }

            float tm = sv[0];
#pragma unroll
            for (int r = 1; r < 16; ++r) tm = fmaxf(tm, sv[r]);
            tm = fmaxf(tm, __shfl_xor(tm, 16, 64));
            tm = fmaxf(tm, __shfl_xor(tm, 32, 64));

            // T13 defer-max: skip rescale while max growth <= 8 (P <= 2^8)
            if (!__all(tm <= m + 8.0f)) {
                const float newm = fmaxf(m, tm);
                const float al = exp2f(m - newm);
                m = newm;
                lsum *= al;
#pragma unroll
                for (int d = 0; d < 4; ++d)
#pragma unroll
                    for (int j = 0; j < 4; ++j) acc[d][j] *= al;
            }

            float ps[16], ts = 0.f;
#pragma unroll
            for (int r = 0; r < 16; ++r) {
                ps[r] = exp2f(sv[r] - m);
                ts += ps[r];
            }
            ts += __shfl_xor(ts, 16, 64);
            ts += __shfl_xor(ts, 32, 64);
            lsum += ts;

            bf16x8 pf[2];
#pragma unroll
            for (int hh = 0; hh < 2; ++hh) {
                const float* p8 = &ps[hh * 8];
                unsigned wsp[2][2];
#pragma unroll
                for (int s = 0; s < 2; ++s)
#pragma unroll
                    for (int p2 = 0; p2 < 2; ++p2)
                        wsp[s][p2] = pkbf(p8[s * 4 + 2 * p2], p8[s * 4 + 2 * p2 + 1]);
                unsigned n0[2], n1[2];
#pragma unroll
                for (int p2 = 0; p2 < 2; ++p2) {
                    unsigned snd = c5 ? wsp[0][p2] : wsp[1][p2];
                    unsigned exch = __shfl_xor((int)snd, 32, 64);
                    n0[p2] = c5 ? exch : wsp[0][p2];
                    n1[p2] = c5 ? wsp[1][p2] : exch;
                }
                unsigned f0[2], f1[2];
#pragma unroll
                for (int p2 = 0; p2 < 2; ++p2) {
                    unsigned snd = c4 ? n0[p2] : n1[p2];
                    unsigned exch = __shfl_xor((int)snd, 16, 64);
                    f0[p2] = c4 ? exch : n0[p2];
                    f1[p2] = c4 ? n1[p2] : exch;
                }
                union { unsigned u[4]; bf16x8 v; } pu;
                pu.u[0] = f0[0]; pu.u[1] = f0[1]; pu.u[2] = f1[0]; pu.u[3] = f1[1];
                pf[hh] = pu.v;
            }

#pragma unroll
            for (int d = 0; d < 4; ++d) {
                acc[d] = __builtin_amdgcn_mfma_f32_16x16x32_bf16(vf[d][0], pf[0], acc[d], 0, 0, 0);
                acc[d] = __builtin_amdgcn_mfma_f32_16x16x32_bf16(vf[d][1], pf[1], acc[d], 0, 0, 0);
            }
            gp++;
        }

        const float inv = 1.0f / lsum;
#pragma unroll
        for (int d = 0; d < 4; ++d) {
            ushort4 o;
            o.x = f2bf(acc[d][0] * inv);
            o.y = f2bf(acc[d][1] * inv);
            o.z = f2bf(acc[d][2] * inv);
            o.w = f2bf(acc[d][3] * inv);
            *(ushort4*)&X[(size_t)(b * SEQ + qg) * DM + h * DK + d * 16 + 4 * lg] = o;
        }
    }
}

extern "C" void kernel_launch(void* const* d_in, const int* in_sizes, int n_in,
                              void* d_out, int out_size, void* d_ws, size_t ws_size,
                              hipStream_t stream) {
    const float* q  = (const float*)d_in[0];
    const float* k  = (const float*)d_in[1];
    const float* v  = (const float*)d_in[2];
    const float* Wq = (const float*)d_in[4];
    const float* bq = (const float*)d_in[5];
    const float* Wk = (const float*)d_in[6];
    const float* bk = (const float*)d_in[7];
    const float* Wv = (const float*)d_in[8];
    const float* bv = (const float*)d_in[9];
    const float* Wo = (const float*)d_in[10];
    const float* bo = (const float*)d_in[11];

    const size_t NEL = (size_t)4 * SEQ * DM;  // 8,388,608 elems per buffer
    const size_t WEL = (size_t)DM * DM;       // 1,048,576 elems per weight
    unsigned short* Qp  = (unsigned short*)d_ws;
    unsigned short* Kp  = Qp + NEL;
    unsigned short* Vp  = Kp + NEL;   // attn output Xp
    unsigned short* Vt  = Vp + NEL;
    unsigned short* Wob = Vt + NEL;
    unsigned short* Xp  = Vp;
    unsigned short* Wqb = (unsigned short*)d_out;  // d_out as scratch until final GEMM
    unsigned short* Wkb = Wqb + WEL;
    unsigned short* Wvb = Wkb + WEL;

    dim3 gb(256);
    hipLaunchKernelGGL(cvt_w, dim3(1024, 4), gb, 0, stream, Wq, Wk, Wv, Wo, Wqb, Wkb, Wvb, Wob);
    hipLaunchKernelGGL((gemm_bt<false, 0>), dim3(512), gb, 0, stream, (const void*)q, Wqb, bq, (void*)Qp, 8192, DM, DM);
    hipLaunchKernelGGL((gemm_bt<false, 0>), dim3(512), gb, 0, stream, (const void*)k, Wkb, bk, (void*)Kp, 8192, DM, DM);
    hipLaunchKernelGGL((gemm_bt<false, 2>), dim3(512), gb, 0, stream, (const void*)v, Wvb, bv, (void*)Vt, 8192, DM, DM);
    hipLaunchKernelGGL(attn, dim3(1024), gb, 0, stream, Qp, Kp, Vt, Xp);
    hipLaunchKernelGGL((gemm_bt<true, 1>), dim3(512), gb, 0, stream, (const void*)Xp, Wob, bo, d_out, 8192, DM, DM);
}

// Round 11
// 256.846 us; speedup vs baseline: 2.6229x; 1.0237x over previous
//
#include <hip/hip_runtime.h>

#define DM 1024
#define SEQ 2048
#define NH 16
#define DK 64

typedef __bf16 bf16x8 __attribute__((ext_vector_type(8)));
typedef float f32x4 __attribute__((ext_vector_type(4)));

// softmax scale folded into Q: 1/sqrt(64) * log2(e)
#define QSCALE 0.1803368801111244f

__device__ inline unsigned short f2bf(float f) {
    unsigned u = __float_as_uint(f);
    u += 0x7fffu + ((u >> 16) & 1u);
    return (unsigned short)(u >> 16);
}

// packed bf16 pair via native casts (compiler emits v_cvt_pk_bf16_f32)
__device__ inline unsigned pkbf(float lo, float hi) {
    union { __bf16 h[2]; unsigned u; } r;
    r.h[0] = (__bf16)lo; r.h[1] = (__bf16)hi;
    return r.u;
}

// fp32 -> bf16 for the four weight matrices (1M elems each), one dispatch.
__global__ __launch_bounds__(256) void cvt_w(const float* __restrict__ s0,
                                             const float* __restrict__ s1,
                                             const float* __restrict__ s2,
                                             const float* __restrict__ s3,
                                             unsigned short* __restrict__ d0,
                                             unsigned short* __restrict__ d1,
                                             unsigned short* __restrict__ d2,
                                             unsigned short* __restrict__ d3) {
    const float* s;
    unsigned short* d;
    switch (blockIdx.y) {
        case 0: s = s0; d = d0; break;
        case 1: s = s1; d = d1; break;
        case 2: s = s2; d = d2; break;
        default: s = s3; d = d3; break;
    }
    int i = (blockIdx.x * 256 + threadIdx.x) * 4;
    float4 v = *(const float4*)(s + i);
    ushort4 o;
    o.x = f2bf(v.x); o.y = f2bf(v.y); o.z = f2bf(v.z); o.w = f2bf(v.w);
    *(ushort4*)(d + i) = o;
}

// Merged Q/K/V projection GEMM: 1536 blocks, segment = bid>>9 selects
// (A, W, bias, C, epilogue). 5-6 blocks/CU co-resident (vs 2 when separate).
// C = A[8192,1024]fp32 @ W[1024,1024]bf16^T + bias.  BK=64, dbuf LDS, T2
// swizzle, 2-phase counted-vmcnt pipeline, XCD-chunked 2D block swizzle.
// seg 0: out bf16 * QSCALE -> Qp ; seg 1: out bf16 -> Kp ; seg 2: Vt[bh][d][s].
__global__ __launch_bounds__(256) void gemm_qkv(
    const float* __restrict__ Aq, const float* __restrict__ Ak,
    const float* __restrict__ Av,
    const unsigned short* __restrict__ Wq2, const unsigned short* __restrict__ Wk2,
    const unsigned short* __restrict__ Wv2,
    const float* __restrict__ bq2, const float* __restrict__ bk2,
    const float* __restrict__ bv2,
    unsigned short* __restrict__ Cq, unsigned short* __restrict__ Ck,
    unsigned short* __restrict__ Cvt) {
    __shared__ unsigned short lds_a[2][128 * 64];
    __shared__ unsigned short lds_w[2][128 * 64];

    const int K = DM, N = DM;
    const int t = threadIdx.x;
    const int lane = t & 63;
    const int w = t >> 6;
    const int wr = w >> 1, wc = w & 1;
    const int bid = blockIdx.x;
    const int seg = bid >> 9;         // 0..2
    const int inner = bid & 511;
    const int xcd = inner & 7;
    const int idx = inner >> 3;
    const int rowBase = (xcd * 8 + (idx >> 3)) * 128;
    const int colBase = (idx & 7) * 128;
    const int l15 = lane & 15;
    const int lg = lane >> 4;
    const int ar = t >> 1, ah = t & 1;
    const int NIT = K >> 6;  // 16

    const float* A = seg == 0 ? Aq : (seg == 1 ? Ak : Av);
    const unsigned short* W = seg == 0 ? Wq2 : (seg == 1 ? Wk2 : Wv2);
    const float* bias = seg == 0 ? bq2 : (seg == 1 ? bk2 : bv2);

    f32x4 acc[4][4] = {};

    auto STAGE_W = [&](int kt, int buf) {
#pragma unroll
        for (int i = 0; i < 4; ++i) {
            const int row = (w * 4 + i) * 8 + (lane >> 3);
            const int sl = lane & 7;
            const unsigned short* src =
                W + (size_t)(colBase + row) * K + kt * 64 + ((sl ^ (row & 7)) * 8);
            __builtin_amdgcn_global_load_lds(src, &lds_w[buf][(w * 4 + i) * 512], 16, 0, 0);
        }
    };
    auto LOADA = [&](int kt, float4* rf) {
        const float* Af = A + (size_t)(rowBase + ar) * K + kt * 64 + ah * 32;
#pragma unroll
        for (int i = 0; i < 4; ++i) {
            rf[2 * i] = *(const float4*)(Af + i * 8);
            rf[2 * i + 1] = *(const float4*)(Af + i * 8 + 4);
        }
    };
    auto WRITEA = [&](const float4* rf, int buf) {
#pragma unroll
        for (int i = 0; i < 4; ++i) {
            union { __bf16 h[8]; uint4 u; } pk;
            pk.h[0] = (__bf16)rf[2 * i].x; pk.h[1] = (__bf16)rf[2 * i].y;
            pk.h[2] = (__bf16)rf[2 * i].z; pk.h[3] = (__bf16)rf[2 * i].w;
            pk.h[4] = (__bf16)rf[2 * i + 1].x; pk.h[5] = (__bf16)rf[2 * i + 1].y;
            pk.h[6] = (__bf16)rf[2 * i + 1].z; pk.h[7] = (__bf16)rf[2 * i + 1].w;
            *(uint4*)&lds_a[buf][ar * 64 + (((ah * 4 + i) ^ (ar & 7)) * 8)] = pk.u;
        }
    };
    auto COMPUTE = [&](int buf) {
#pragma unroll
        for (int kh = 0; kh < 2; ++kh) {
            bf16x8 af[4], wf[4];
#pragma unroll
            for (int m = 0; m < 4; ++m)
                af[m] = *(const bf16x8*)&lds_a[buf][(wr * 64 + m * 16 + l15) * 64 +
                                                   (((kh * 4 + lg) ^ (l15 & 7)) * 8)];
#pragma unroll
            for (int n = 0; n < 4; ++n)
                wf[n] = *(const bf16x8*)&lds_w[buf][(wc * 64 + n * 16 + l15) * 64 +
                                                   (((kh * 4 + lg) ^ (l15 & 7)) * 8)];
#pragma unroll
            for (int m = 0; m < 4; ++m)
#pragma unroll
                for (int n = 0; n < 4; ++n)
                    acc[m][n] = __builtin_amdgcn_mfma_f32_16x16x32_bf16(af[m], wf[n],
                                                                        acc[m][n], 0, 0, 0);
        }
    };

    float4 ra[8], rb[8];
    STAGE_W(0, 0);
    LOADA(0, ra);
    for (int kt = 0; kt < NIT; kt += 2) {
        if (kt + 1 < NIT) {
            STAGE_W(kt + 1, 1);
            LOADA(kt + 1, rb);
            asm volatile("s_waitcnt vmcnt(12)" ::: "memory");
        } else {
            asm volatile("s_waitcnt vmcnt(0)" ::: "memory");
        }
        WRITEA(ra, 0);
        asm volatile("s_waitcnt lgkmcnt(0)" ::: "memory");
        __builtin_amdgcn_s_barrier();
        COMPUTE(0);
        __builtin_amdgcn_s_barrier();
        if (kt + 2 < NIT) {
            STAGE_W(kt + 2, 0);
            LOADA(kt + 2, ra);
            asm volatile("s_waitcnt vmcnt(12)" ::: "memory");
        } else {
            asm volatile("s_waitcnt vmcnt(0)" ::: "memory");
        }
        WRITEA(rb, 1);
        asm volatile("s_waitcnt lgkmcnt(0)" ::: "memory");
        __builtin_amdgcn_s_barrier();
        COMPUTE(1);
        __builtin_amdgcn_s_barrier();
    }

    const float oscale = seg == 0 ? QSCALE : 1.0f;
#pragma unroll
    for (int m = 0; m < 4; ++m) {
        int row = rowBase + wr * 64 + m * 16 + lg * 4;
#pragma unroll
        for (int n = 0; n < 4; ++n) {
            int col = colBase + wc * 64 + n * 16 + l15;
            float bv = bias[col];
            if (seg == 2) {
                const int bh = (row >> 11) * NH + (col >> 6);
                const int dloc = col & 63;
                const int s = row & (SEQ - 1);
                ushort4 o;
                o.x = f2bf(acc[m][n][0] + bv);
                o.y = f2bf(acc[m][n][1] + bv);
                o.z = f2bf(acc[m][n][2] + bv);
                o.w = f2bf(acc[m][n][3] + bv);
                *(ushort4*)(Cvt + ((size_t)bh * DK + dloc) * SEQ + s) = o;
            } else {
                unsigned short* C = seg == 0 ? Cq : Ck;
#pragma unroll
                for (int j = 0; j < 4; ++j)
                    C[(size_t)(row + j) * N + col] = f2bf((acc[m][n][j] + bv) * oscale);
            }
        }
    }
}

// Final GEMM: C[8192,1024]f32 = X[8192,1024]bf16 @ Wo[1024,1024]bf16^T + bo.
__global__ __launch_bounds__(256) void gemm_out(const unsigned short* __restrict__ Av,
                                                const unsigned short* __restrict__ W,
                                                const float* __restrict__ bias,
                                                float* __restrict__ Cv) {
    __shared__ unsigned short lds_a[2][128 * 64];
    __shared__ unsigned short lds_w[2][128 * 64];

    const int K = DM, N = DM;
    const int t = threadIdx.x;
    const int lane = t & 63;
    const int w = t >> 6;
    const int wr = w >> 1, wc = w & 1;
    const int bid = blockIdx.x;
    const int xcd = bid & 7;
    const int idx = bid >> 3;
    const int rowBase = (xcd * 8 + (idx >> 3)) * 128;
    const int colBase = (idx & 7) * 128;
    const int l15 = lane & 15;
    const int lg = lane >> 4;
    const int NIT = K >> 6;

    f32x4 acc[4][4] = {};

    auto STAGE = [&](const unsigned short* M0, unsigned short* ldsb, int kt) {
#pragma unroll
        for (int i = 0; i < 4; ++i) {
            const int row = (w * 4 + i) * 8 + (lane >> 3);
            const int sl = lane & 7;
            const unsigned short* src =
                M0 + (size_t)row * K + kt * 64 + ((sl ^ (row & 7)) * 8);
            __builtin_amdgcn_global_load_lds(src, ldsb + (w * 4 + i) * 512, 16, 0, 0);
        }
    };
    auto COMPUTE = [&](int buf) {
#pragma unroll
        for (int kh = 0; kh < 2; ++kh) {
            bf16x8 af[4], wf[4];
#pragma unroll
            for (int m = 0; m < 4; ++m)
                af[m] = *(const bf16x8*)&lds_a[buf][(wr * 64 + m * 16 + l15) * 64 +
                                                   (((kh * 4 + lg) ^ (l15 & 7)) * 8)];
#pragma unroll
            for (int n = 0; n < 4; ++n)
                wf[n] = *(const bf16x8*)&lds_w[buf][(wc * 64 + n * 16 + l15) * 64 +
                                                   (((kh * 4 + lg) ^ (l15 & 7)) * 8)];
#pragma unroll
            for (int m = 0; m < 4; ++m)
#pragma unroll
                for (int n = 0; n < 4; ++n)
                    acc[m][n] = __builtin_amdgcn_mfma_f32_16x16x32_bf16(af[m], wf[n],
                                                                        acc[m][n], 0, 0, 0);
        }
    };

    const unsigned short* Arow = Av + (size_t)rowBase * K;
    const unsigned short* Wrow = W + (size_t)colBase * K;
    STAGE(Wrow, lds_w[0], 0);
    STAGE(Arow, lds_a[0], 0);
    for (int kt = 0; kt < NIT; ++kt) {
        const int cur = kt & 1;
        if (kt + 1 < NIT) {
            STAGE(Wrow, lds_w[cur ^ 1], kt + 1);
            STAGE(Arow, lds_a[cur ^ 1], kt + 1);
            asm volatile("s_waitcnt vmcnt(8)" ::: "memory");
        } else {
            asm volatile("s_waitcnt vmcnt(0)" ::: "memory");
        }
        __builtin_amdgcn_s_barrier();
        COMPUTE(cur);
        __builtin_amdgcn_s_barrier();
    }

#pragma unroll
    for (int m = 0; m < 4; ++m) {
        int row = rowBase + wr * 64 + m * 16 + lg * 4;
#pragma unroll
        for (int n = 0; n < 4; ++n) {
            int col = colBase + wc * 64 + n * 16 + l15;
            float bv = bias[col];
#pragma unroll
            for (int j = 0; j < 4; ++j)
                Cv[(size_t)(row + j) * N + col] = acc[m][n][j] + bv;
        }
    }
}

// Flash attention, causal, swapped-operand, LDS-staged K/V, double-buffered.
// Q pre-scaled by QSCALE (scores land in exp2 domain directly).
// lsum via ones-row MFMA into accS (no sum tree / shuffles).
__global__ __launch_bounds__(256) void attn(const unsigned short* __restrict__ Q,
                                            const unsigned short* __restrict__ K,
                                            const unsigned short* __restrict__ Vt,
                                            unsigned short* __restrict__ X) {
    __shared__ unsigned short k_lds[2][64 * 64];
    __shared__ unsigned short v_lds[2][64 * 64];

    const int t = threadIdx.x;
    const int lane = t & 63;
    const int w = t >> 6;
    const int l15 = lane & 15, lg = lane >> 4;
    const int c4 = (lane >> 4) & 1, c5 = (lane >> 5) & 1;

    const int orig = blockIdx.x;
    const int flat = (orig & 7) * 128 + (orig >> 3);
    const int bh = flat >> 4;
    const int pr = flat & 15;
    const int b = bh >> 4, h = bh & 15;

    const unsigned short* Qb = Q + (size_t)b * SEQ * DM + h * DK;
    const unsigned short* Kb = K + (size_t)b * SEQ * DM + h * DK;
    const unsigned short* Vb = Vt + (size_t)bh * DK * SEQ;

    const int sr = t >> 3;
    const int sc8 = (t & 7) * 8;
    const int sxo = (sr & 7) * 8;
    const int xork = (l15 & 7) * 8;

    // ones A-fragment (1.0 bf16 = 0x3F80 in all 8 slots)
    union { unsigned short us[8]; bf16x8 v; } ou;
#pragma unroll
    for (int i = 0; i < 8; ++i) ou.us[i] = 0x3F80;
    const bf16x8 onesf = ou.v;

    bf16x8 kr0, kr1, vr0, vr1;
    int gp = 0;

    auto LOADT = [&](int kv0) {
        kr0 = *(const bf16x8*)(Kb + (size_t)(kv0 + sr) * DM + sc8);
        kr1 = *(const bf16x8*)(Kb + (size_t)(kv0 + 32 + sr) * DM + sc8);
        vr0 = *(const bf16x8*)(Vb + (size_t)sr * SEQ + kv0 + sc8);
        vr1 = *(const bf16x8*)(Vb + (size_t)(32 + sr) * SEQ + kv0 + sc8);
    };

    LOADT(0);

    for (int task = 0; task < 2; ++task) {
        const int qt = task ? 31 - pr : pr;
        const int qrow0 = qt * 64 + w * 16;
        const int qg = qrow0 + l15;

        const bf16x8 qf0 = *(const bf16x8*)(Qb + (size_t)(qrow0 + l15) * DM + lg * 8);
        const bf16x8 qf1 = *(const bf16x8*)(Qb + (size_t)(qrow0 + l15) * DM + lg * 8 + 32);

        f32x4 acc[4] = {};
        f32x4 accS = {};
        float m = -1e30f;
        const int nt = qt + 1;

        for (int tile = 0; tile < nt; ++tile) {
            const int kv0 = tile << 6;
            unsigned short* kl = k_lds[gp & 1];
            unsigned short* vl = v_lds[gp & 1];
            *(bf16x8*)&kl[sr * 64 + (sc8 ^ sxo)] = kr0;
            *(bf16x8*)&kl[(sr + 32) * 64 + (sc8 ^ sxo)] = kr1;
            *(bf16x8*)&vl[sr * 64 + (sc8 ^ sxo)] = vr0;
            *(bf16x8*)&vl[(sr + 32) * 64 + (sc8 ^ sxo)] = vr1;
            __syncthreads();

            if (tile + 1 < nt)
                LOADT((tile + 1) << 6);
            else if (task == 0)
                LOADT(0);

            f32x4 st[4];
#pragma unroll
            for (int s = 0; s < 4; ++s) {
                const int rb2 = (s * 16 + l15) * 64;
                bf16x8 ka = *(const bf16x8*)&kl[rb2 + ((lg * 8) ^ xork)];
                bf16x8 kb2 = *(const bf16x8*)&kl[rb2 + ((32 + lg * 8) ^ xork)];
                f32x4 z = {};
                z = __builtin_amdgcn_mfma_f32_16x16x32_bf16(ka, qf0, z, 0, 0, 0);
                st[s] = __builtin_amdgcn_mfma_f32_16x16x32_bf16(kb2, qf1, st[s] = z, 0, 0, 0);
            }

            bf16x8 vf[4][2];
#pragma unroll
            for (int d = 0; d < 4; ++d) {
                const int rb2 = (d * 16 + l15) * 64;
                vf[d][0] = *(const bf16x8*)&vl[rb2 + ((lg * 8) ^ xork)];
                vf[d][1] = *(const bf16x8*)&vl[rb2 + ((32 + lg * 8) ^ xork)];
            }

            float sv[16];
#pragma unroll
            for (int s = 0; s < 4; ++s)
#pragma unroll
                for (int j = 0; j < 4; ++j) sv[s * 4 + j] = st[s][j];

            if (kv0 + 63 > qrow0) {
#pragma unroll
                for (int s = 0; s < 4; ++s)
#pragma unroll
                    for (int j = 0; j < 4; ++j)
                        if (kv0 + s * 16 + 4 * lg + j > qg) sv[s * 4 + j] = -1e30f;
            }

            // max tree via max3 triples (9 ops) + 2 shuffles
            float m1 = fmaxf(fmaxf(sv[0], sv[1]), sv[2]);
            float m2 = fmaxf(fmaxf(sv[3], sv[4]), sv[5]);
            float m3 = fmaxf(fmaxf(sv[6], sv[7]), sv[8]);
            float m4 = fmaxf(fmaxf(sv[9], sv[10]), sv[11]);
            float m5 = fmaxf(fmaxf(sv[12], sv[13]), sv[14]);
            float tm = fmaxf(fmaxf(fmaxf(m1, m2), fmaxf(m3, m4)), fmaxf(m5, sv[15]));
            tm = fmaxf(tm, __shfl_xor(tm, 16, 64));
            tm = fmaxf(tm, __shfl_xor(tm, 32, 64));

            // T13 defer-max: skip rescale while max growth <= 8 (P <= 2^8)
            if (!__all(tm <= m + 8.0f)) {
                const float newm = fmaxf(m, tm);
                const float al = exp2f(m - newm);
                m = newm;
#pragma unroll
                for (int d = 0; d < 4; ++d)
#pragma unroll
                    for (int j = 0; j < 4; ++j) acc[d][j] *= al;
#pragma unroll
                for (int j = 0; j < 4; ++j) accS[j] *= al;
            }

            float ps[16];
#pragma unroll
            for (int r = 0; r < 16; ++r) ps[r] = exp2f(sv[r] - m);

            bf16x8 pf[2];
#pragma unroll
            for (int hh = 0; hh < 2; ++hh) {
                const float* p8 = &ps[hh * 8];
                unsigned wsp[2][2];
#pragma unroll
                for (int s = 0; s < 2; ++s)
#pragma unroll
                    for (int p2 = 0; p2 < 2; ++p2)
                        wsp[s][p2] = pkbf(p8[s * 4 + 2 * p2], p8[s * 4 + 2 * p2 + 1]);
                unsigned n0[2], n1[2];
#pragma unroll
                for (int p2 = 0; p2 < 2; ++p2) {
                    unsigned snd = c5 ? wsp[0][p2] : wsp[1][p2];
                    unsigned exch = __shfl_xor((int)snd, 32, 64);
                    n0[p2] = c5 ? exch : wsp[0][p2];
                    n1[p2] = c5 ? wsp[1][p2] : exch;
                }
                unsigned f0[2], f1[2];
#pragma unroll
                for (int p2 = 0; p2 < 2; ++p2) {
                    unsigned snd = c4 ? n0[p2] : n1[p2];
                    unsigned exch = __shfl_xor((int)snd, 16, 64);
                    f0[p2] = c4 ? exch : n0[p2];
                    f1[p2] = c4 ? n1[p2] : exch;
                }
                union { unsigned u[4]; bf16x8 v; } pu;
                pu.u[0] = f0[0]; pu.u[1] = f0[1]; pu.u[2] = f1[0]; pu.u[3] = f1[1];
                pf[hh] = pu.v;
            }

#pragma unroll
            for (int d = 0; d < 4; ++d) {
                acc[d] = __builtin_amdgcn_mfma_f32_16x16x32_bf16(vf[d][0], pf[0], acc[d], 0, 0, 0);
                acc[d] = __builtin_amdgcn_mfma_f32_16x16x32_bf16(vf[d][1], pf[1], acc[d], 0, 0, 0);
            }
            // row-sum of P via ones-row MFMA (replaces sum tree + shuffles)
            accS = __builtin_amdgcn_mfma_f32_16x16x32_bf16(onesf, pf[0], accS, 0, 0, 0);
            accS = __builtin_amdgcn_mfma_f32_16x16x32_bf16(onesf, pf[1], accS, 0, 0, 0);
            gp++;
        }

        const float inv = 1.0f / accS[0];
#pragma unroll
        for (int d = 0; d < 4; ++d) {
            ushort4 o;
            o.x = f2bf(acc[d][0] * inv);
            o.y = f2bf(acc[d][1] * inv);
            o.z = f2bf(acc[d][2] * inv);
            o.w = f2bf(acc[d][3] * inv);
            *(ushort4*)&X[(size_t)(b * SEQ + qg) * DM + h * DK + d * 16 + 4 * lg] = o;
        }
    }
}

extern "C" void kernel_launch(void* const* d_in, const int* in_sizes, int n_in,
                              void* d_out, int out_size, void* d_ws, size_t ws_size,
                              hipStream_t stream) {
    const float* q  = (const float*)d_in[0];
    const float* k  = (const float*)d_in[1];
    const float* v  = (const float*)d_in[2];
    const float* Wq = (const float*)d_in[4];
    const float* bq = (const float*)d_in[5];
    const float* Wk = (const float*)d_in[6];
    const float* bk = (const float*)d_in[7];
    const float* Wv = (const float*)d_in[8];
    const float* bv = (const float*)d_in[9];
    const float* Wo = (const float*)d_in[10];
    const float* bo = (const float*)d_in[11];

    const size_t NEL = (size_t)4 * SEQ * DM;  // 8,388,608 elems per buffer
    const size_t WEL = (size_t)DM * DM;       // 1,048,576 elems per weight
    unsigned short* Qp  = (unsigned short*)d_ws;
    unsigned short* Kp  = Qp + NEL;
    unsigned short* Vp  = Kp + NEL;   // attn output Xp
    unsigned short* Vt  = Vp + NEL;
    unsigned short* Wob = Vt + NEL;
    unsigned short* Xp  = Vp;
    unsigned short* Wqb = (unsigned short*)d_out;  // d_out as scratch until final GEMM
    unsigned short* Wkb = Wqb + WEL;
    unsigned short* Wvb = Wkb + WEL;

    dim3 gb(256);
    hipLaunchKernelGGL(cvt_w, dim3(1024, 4), gb, 0, stream, Wq, Wk, Wv, Wo, Wqb, Wkb, Wvb, Wob);
    hipLaunchKernelGGL(gemm_qkv, dim3(1536), gb, 0, stream, q, k, v, Wqb, Wkb, Wvb,
                       bq, bk, bv, Qp, Kp, Vt);
    hipLaunchKernelGGL(attn, dim3(1024), gb, 0, stream, Qp, Kp, Vt, Xp);
    hipLaunchKernelGGL(gemm_out, dim3(512), gb, 0, stream, Xp, Wob, bo, (float*)d_out);
}

// Round 12
// 225.962 us; speedup vs baseline: 2.9814x; 1.1367x over previous
//
#include <hip/hip_runtime.h>

#define DM 1024
#define SEQ 2048
#define NH 16
#define DK 64

typedef __bf16 bf16x8 __attribute__((ext_vector_type(8)));
typedef float f32x4 __attribute__((ext_vector_type(4)));

// softmax scale folded into Q: 1/sqrt(64) * log2(e)
#define QSCALE 0.1803368801111244f

__device__ inline unsigned short f2bf(float f) {
    unsigned u = __float_as_uint(f);
    u += 0x7fffu + ((u >> 16) & 1u);
    return (unsigned short)(u >> 16);
}

// packed bf16 pair via native casts (compiler emits v_cvt_pk_bf16_f32)
__device__ inline unsigned pkbf(float lo, float hi) {
    union { __bf16 h[2]; unsigned u; } r;
    r.h[0] = (__bf16)lo; r.h[1] = (__bf16)hi;
    return r.u;
}

// fp32 -> bf16 for the four weight matrices (1M elems each), one dispatch.
__global__ __launch_bounds__(256) void cvt_w(const float* __restrict__ s0,
                                             const float* __restrict__ s1,
                                             const float* __restrict__ s2,
                                             const float* __restrict__ s3,
                                             unsigned short* __restrict__ d0,
                                             unsigned short* __restrict__ d1,
                                             unsigned short* __restrict__ d2,
                                             unsigned short* __restrict__ d3) {
    const float* s;
    unsigned short* d;
    switch (blockIdx.y) {
        case 0: s = s0; d = d0; break;
        case 1: s = s1; d = d1; break;
        case 2: s = s2; d = d2; break;
        default: s = s3; d = d3; break;
    }
    int i = (blockIdx.x * 256 + threadIdx.x) * 4;
    float4 v = *(const float4*)(s + i);
    ushort4 o;
    o.x = f2bf(v.x); o.y = f2bf(v.y); o.z = f2bf(v.z); o.w = f2bf(v.w);
    *(ushort4*)(d + i) = o;
}

// C[M,N] = A[M,K] @ W[N,K]^T + bias[N].  W bf16.  128x128 tile, BK=64,
// dbuf LDS (64KB), T2 slot-swizzle, 2-phase counted-vmcnt pipeline.
// 512 THREADS / 8 waves (4 row-strips x 2 col-strips, acc[2][4] per wave):
// 2 blocks/CU x 8 waves = 4 waves/SIMD -> double latency hiding vs 4-wave.
// OUT_MODE: 0 bf16 row-major (*oscale), 1 f32 row-major, 2 bf16 Vt[bh][d][s].
template <bool A_BF16, int OUT_MODE>
__global__ __launch_bounds__(512) void gemm_bt(const void* __restrict__ Av,
                                               const unsigned short* __restrict__ W,
                                               const float* __restrict__ bias,
                                               void* __restrict__ Cv,
                                               float oscale) {
    __shared__ unsigned short lds_a[2][128 * 64];
    __shared__ unsigned short lds_w[2][128 * 64];

    const int K = DM, N = DM;
    const int t = threadIdx.x;
    const int lane = t & 63;
    const int w = t >> 6;           // 0..7
    const int wr = w >> 1;          // 0..3 (32-row strip)
    const int wc = w & 1;           // 0..1 (64-col strip)
    const int bid = blockIdx.x;
    const int xcd = bid & 7;
    const int idx = bid >> 3;
    const int rowBase = (xcd * 8 + (idx >> 3)) * 128;
    const int colBase = (idx & 7) * 128;
    const int l15 = lane & 15;
    const int lg = lane >> 4;
    const int ar = t >> 2, aq = t & 3;  // fp32-A: row 0..127, quarter (16 cols)
    const int NIT = K >> 6;             // 16

    f32x4 acc[2][4] = {};

    auto STAGE_W = [&](int kt, int buf) {
#pragma unroll
        for (int i = 0; i < 2; ++i) {
            const int row = (w * 2 + i) * 8 + (lane >> 3);
            const int sl = lane & 7;
            const unsigned short* src =
                W + (size_t)(colBase + row) * K + kt * 64 + ((sl ^ (row & 7)) * 8);
            __builtin_amdgcn_global_load_lds(src, &lds_w[buf][(w * 2 + i) * 512], 16, 0, 0);
        }
    };
    auto STAGE_A16 = [&](int kt, int buf) {
#pragma unroll
        for (int i = 0; i < 2; ++i) {
            const int row = (w * 2 + i) * 8 + (lane >> 3);
            const int sl = lane & 7;
            const unsigned short* src = (const unsigned short*)Av +
                (size_t)(rowBase + row) * K + kt * 64 + ((sl ^ (row & 7)) * 8);
            __builtin_amdgcn_global_load_lds(src, &lds_a[buf][(w * 2 + i) * 512], 16, 0, 0);
        }
    };
    auto LOADA = [&](int kt, float4* rf) {
        const float* Af = (const float*)Av + (size_t)(rowBase + ar) * K + kt * 64 + aq * 16;
#pragma unroll
        for (int i = 0; i < 4; ++i) rf[i] = *(const float4*)(Af + i * 4);
    };
    auto WRITEA = [&](const float4* rf, int buf) {
#pragma unroll
        for (int i = 0; i < 2; ++i) {
            union { __bf16 h[8]; uint4 u; } pk;
            pk.h[0] = (__bf16)rf[2 * i].x; pk.h[1] = (__bf16)rf[2 * i].y;
            pk.h[2] = (__bf16)rf[2 * i].z; pk.h[3] = (__bf16)rf[2 * i].w;
            pk.h[4] = (__bf16)rf[2 * i + 1].x; pk.h[5] = (__bf16)rf[2 * i + 1].y;
            pk.h[6] = (__bf16)rf[2 * i + 1].z; pk.h[7] = (__bf16)rf[2 * i + 1].w;
            *(uint4*)&lds_a[buf][ar * 64 + (((aq * 2 + i) ^ (ar & 7)) * 8)] = pk.u;
        }
    };
    auto COMPUTE = [&](int buf) {
#pragma unroll
        for (int kh = 0; kh < 2; ++kh) {
            bf16x8 af[2], wf[4];
#pragma unroll
            for (int m = 0; m < 2; ++m)
                af[m] = *(const bf16x8*)&lds_a[buf][(wr * 32 + m * 16 + l15) * 64 +
                                                   (((kh * 4 + lg) ^ (l15 & 7)) * 8)];
#pragma unroll
            for (int n = 0; n < 4; ++n)
                wf[n] = *(const bf16x8*)&lds_w[buf][(wc * 64 + n * 16 + l15) * 64 +
                                                   (((kh * 4 + lg) ^ (l15 & 7)) * 8)];
#pragma unroll
            for (int m = 0; m < 2; ++m)
#pragma unroll
                for (int n = 0; n < 4; ++n)
                    acc[m][n] = __builtin_amdgcn_mfma_f32_16x16x32_bf16(af[m], wf[n],
                                                                        acc[m][n], 0, 0, 0);
        }
    };

    if (A_BF16) {
        STAGE_W(0, 0);
        STAGE_A16(0, 0);
        for (int kt = 0; kt < NIT; ++kt) {
            const int cur = kt & 1;
            if (kt + 1 < NIT) {
                STAGE_W(kt + 1, cur ^ 1);
                STAGE_A16(kt + 1, cur ^ 1);
                asm volatile("s_waitcnt vmcnt(4)" ::: "memory");
            } else {
                asm volatile("s_waitcnt vmcnt(0)" ::: "memory");
            }
            __builtin_amdgcn_s_barrier();
            COMPUTE(cur);
            __builtin_amdgcn_s_barrier();
        }
    } else {
        float4 ra[4], rb[4];
        STAGE_W(0, 0);
        LOADA(0, ra);
        for (int kt = 0; kt < NIT; kt += 2) {  // NIT = 16, even
            if (kt + 1 < NIT) {
                STAGE_W(kt + 1, 1);
                LOADA(kt + 1, rb);
                asm volatile("s_waitcnt vmcnt(6)" ::: "memory");
            } else {
                asm volatile("s_waitcnt vmcnt(0)" ::: "memory");
            }
            WRITEA(ra, 0);
            asm volatile("s_waitcnt lgkmcnt(0)" ::: "memory");
            __builtin_amdgcn_s_barrier();
            COMPUTE(0);
            __builtin_amdgcn_s_barrier();
            if (kt + 2 < NIT) {
                STAGE_W(kt + 2, 0);
                LOADA(kt + 2, ra);
                asm volatile("s_waitcnt vmcnt(6)" ::: "memory");
            } else {
                asm volatile("s_waitcnt vmcnt(0)" ::: "memory");
            }
            WRITEA(rb, 1);
            asm volatile("s_waitcnt lgkmcnt(0)" ::: "memory");
            __builtin_amdgcn_s_barrier();
            COMPUTE(1);
            __builtin_amdgcn_s_barrier();
        }
    }

#pragma unroll
    for (int m = 0; m < 2; ++m) {
        int row = rowBase + wr * 32 + m * 16 + lg * 4;
#pragma unroll
        for (int n = 0; n < 4; ++n) {
            int col = colBase + wc * 64 + n * 16 + l15;
            float bv = bias[col];
            if (OUT_MODE == 2) {
                const int bh = (row >> 11) * NH + (col >> 6);
                const int dloc = col & 63;
                const int s = row & (SEQ - 1);
                ushort4 o;
                o.x = f2bf(acc[m][n][0] + bv);
                o.y = f2bf(acc[m][n][1] + bv);
                o.z = f2bf(acc[m][n][2] + bv);
                o.w = f2bf(acc[m][n][3] + bv);
                *(ushort4*)((unsigned short*)Cv + ((size_t)bh * DK + dloc) * SEQ + s) = o;
            } else if (OUT_MODE == 1) {
#pragma unroll
                for (int j = 0; j < 4; ++j)
                    ((float*)Cv)[(size_t)(row + j) * N + col] = acc[m][n][j] + bv;
            } else {
#pragma unroll
                for (int j = 0; j < 4; ++j)
                    ((unsigned short*)Cv)[(size_t)(row + j) * N + col] =
                        f2bf((acc[m][n][j] + bv) * oscale);
            }
        }
    }
}

// Flash attention, causal, swapped-operand, LDS-staged K/V, double-buffered.
// Q pre-scaled by QSCALE; lsum via ones-row MFMA; max3 tree; T13 defer-max.
__global__ __launch_bounds__(256) void attn(const unsigned short* __restrict__ Q,
                                            const unsigned short* __restrict__ K,
                                            const unsigned short* __restrict__ Vt,
                                            unsigned short* __restrict__ X) {
    __shared__ unsigned short k_lds[2][64 * 64];
    __shared__ unsigned short v_lds[2][64 * 64];

    const int t = threadIdx.x;
    const int lane = t & 63;
    const int w = t >> 6;
    const int l15 = lane & 15, lg = lane >> 4;
    const int c4 = (lane >> 4) & 1, c5 = (lane >> 5) & 1;

    const int orig = blockIdx.x;
    const int flat = (orig & 7) * 128 + (orig >> 3);
    const int bh = flat >> 4;
    const int pr = flat & 15;
    const int b = bh >> 4, h = bh & 15;

    const unsigned short* Qb = Q + (size_t)b * SEQ * DM + h * DK;
    const unsigned short* Kb = K + (size_t)b * SEQ * DM + h * DK;
    const unsigned short* Vb = Vt + (size_t)bh * DK * SEQ;

    const int sr = t >> 3;
    const int sc8 = (t & 7) * 8;
    const int sxo = (sr & 7) * 8;
    const int xork = (l15 & 7) * 8;

    union { unsigned short us[8]; bf16x8 v; } ou;
#pragma unroll
    for (int i = 0; i < 8; ++i) ou.us[i] = 0x3F80;
    const bf16x8 onesf = ou.v;

    bf16x8 kr0, kr1, vr0, vr1;
    int gp = 0;

    auto LOADT = [&](int kv0) {
        kr0 = *(const bf16x8*)(Kb + (size_t)(kv0 + sr) * DM + sc8);
        kr1 = *(const bf16x8*)(Kb + (size_t)(kv0 + 32 + sr) * DM + sc8);
        vr0 = *(const bf16x8*)(Vb + (size_t)sr * SEQ + kv0 + sc8);
        vr1 = *(const bf16x8*)(Vb + (size_t)(32 + sr) * SEQ + kv0 + sc8);
    };

    LOADT(0);

    for (int task = 0; task < 2; ++task) {
        const int qt = task ? 31 - pr : pr;
        const int qrow0 = qt * 64 + w * 16;
        const int qg = qrow0 + l15;

        const bf16x8 qf0 = *(const bf16x8*)(Qb + (size_t)(qrow0 + l15) * DM + lg * 8);
        const bf16x8 qf1 = *(const bf16x8*)(Qb + (size_t)(qrow0 + l15) * DM + lg * 8 + 32);

        f32x4 acc[4] = {};
        f32x4 accS = {};
        float m = -1e30f;
        const int nt = qt + 1;

        for (int tile = 0; tile < nt; ++tile) {
            const int kv0 = tile << 6;
            unsigned short* kl = k_lds[gp & 1];
            unsigned short* vl = v_lds[gp & 1];
            *(bf16x8*)&kl[sr * 64 + (sc8 ^ sxo)] = kr0;
            *(bf16x8*)&kl[(sr + 32) * 64 + (sc8 ^ sxo)] = kr1;
            *(bf16x8*)&vl[sr * 64 + (sc8 ^ sxo)] = vr0;
            *(bf16x8*)&vl[(sr + 32) * 64 + (sc8 ^ sxo)] = vr1;
            __syncthreads();

            if (tile + 1 < nt)
                LOADT((tile + 1) << 6);
            else if (task == 0)
                LOADT(0);

            f32x4 st[4];
#pragma unroll
            for (int s = 0; s < 4; ++s) {
                const int rb2 = (s * 16 + l15) * 64;
                bf16x8 ka = *(const bf16x8*)&kl[rb2 + ((lg * 8) ^ xork)];
                bf16x8 kb2 = *(const bf16x8*)&kl[rb2 + ((32 + lg * 8) ^ xork)];
                f32x4 z = {};
                z = __builtin_amdgcn_mfma_f32_16x16x32_bf16(ka, qf0, z, 0, 0, 0);
                st[s] = __builtin_amdgcn_mfma_f32_16x16x32_bf16(kb2, qf1, z, 0, 0, 0);
            }

            bf16x8 vf[4][2];
#pragma unroll
            for (int d = 0; d < 4; ++d) {
                const int rb2 = (d * 16 + l15) * 64;
                vf[d][0] = *(const bf16x8*)&vl[rb2 + ((lg * 8) ^ xork)];
                vf[d][1] = *(const bf16x8*)&vl[rb2 + ((32 + lg * 8) ^ xork)];
            }

            float sv[16];
#pragma unroll
            for (int s = 0; s < 4; ++s)
#pragma unroll
                for (int j = 0; j < 4; ++j) sv[s * 4 + j] = st[s][j];

            if (kv0 + 63 > qrow0) {
#pragma unroll
                for (int s = 0; s < 4; ++s)
#pragma unroll
                    for (int j = 0; j < 4; ++j)
                        if (kv0 + s * 16 + 4 * lg + j > qg) sv[s * 4 + j] = -1e30f;
            }

            float m1 = fmaxf(fmaxf(sv[0], sv[1]), sv[2]);
            float m2 = fmaxf(fmaxf(sv[3], sv[4]), sv[5]);
            float m3 = fmaxf(fmaxf(sv[6], sv[7]), sv[8]);
            float m4 = fmaxf(fmaxf(sv[9], sv[10]), sv[11]);
            float m5 = fmaxf(fmaxf(sv[12], sv[13]), sv[14]);
            float tm = fmaxf(fmaxf(fmaxf(m1, m2), fmaxf(m3, m4)), fmaxf(m5, sv[15]));
            tm = fmaxf(tm, __shfl_xor(tm, 16, 64));
            tm = fmaxf(tm, __shfl_xor(tm, 32, 64));

            if (!__all(tm <= m + 8.0f)) {
                const float newm = fmaxf(m, tm);
                const float al = exp2f(m - newm);
                m = newm;
#pragma unroll
                for (int d = 0; d < 4; ++d)
#pragma unroll
                    for (int j = 0; j < 4; ++j) acc[d][j] *= al;
#pragma unroll
                for (int j = 0; j < 4; ++j) accS[j] *= al;
            }

            float ps[16];
#pragma unroll
            for (int r = 0; r < 16; ++r) ps[r] = exp2f(sv[r] - m);

            bf16x8 pf[2];
#pragma unroll
            for (int hh = 0; hh < 2; ++hh) {
                const float* p8 = &ps[hh * 8];
                unsigned wsp[2][2];
#pragma unroll
                for (int s = 0; s < 2; ++s)
#pragma unroll
                    for (int p2 = 0; p2 < 2; ++p2)
                        wsp[s][p2] = pkbf(p8[s * 4 + 2 * p2], p8[s * 4 + 2 * p2 + 1]);
                unsigned n0[2], n1[2];
#pragma unroll
                for (int p2 = 0; p2 < 2; ++p2) {
                    unsigned snd = c5 ? wsp[0][p2] : wsp[1][p2];
                    unsigned exch = __shfl_xor((int)snd, 32, 64);
                    n0[p2] = c5 ? exch : wsp[0][p2];
                    n1[p2] = c5 ? wsp[1][p2] : exch;
                }
                unsigned f0[2], f1[2];
#pragma unroll
                for (int p2 = 0; p2 < 2; ++p2) {
                    unsigned snd = c4 ? n0[p2] : n1[p2];
                    unsigned exch = __shfl_xor((int)snd, 16, 64);
                    f0[p2] = c4 ? exch : n0[p2];
                    f1[p2] = c4 ? n1[p2] : exch;
                }
                union { unsigned u[4]; bf16x8 v; } pu;
                pu.u[0] = f0[0]; pu.u[1] = f0[1]; pu.u[2] = f1[0]; pu.u[3] = f1[1];
                pf[hh] = pu.v;
            }

#pragma unroll
            for (int d = 0; d < 4; ++d) {
                acc[d] = __builtin_amdgcn_mfma_f32_16x16x32_bf16(vf[d][0], pf[0], acc[d], 0, 0, 0);
                acc[d] = __builtin_amdgcn_mfma_f32_16x16x32_bf16(vf[d][1], pf[1], acc[d], 0, 0, 0);
            }
            accS = __builtin_amdgcn_mfma_f32_16x16x32_bf16(onesf, pf[0], accS, 0, 0, 0);
            accS = __builtin_amdgcn_mfma_f32_16x16x32_bf16(onesf, pf[1], accS, 0, 0, 0);
            gp++;
        }

        const float inv = 1.0f / accS[0];
#pragma unroll
        for (int d = 0; d < 4; ++d) {
            ushort4 o;
            o.x = f2bf(acc[d][0] * inv);
            o.y = f2bf(acc[d][1] * inv);
            o.z = f2bf(acc[d][2] * inv);
            o.w = f2bf(acc[d][3] * inv);
            *(ushort4*)&X[(size_t)(b * SEQ + qg) * DM + h * DK + d * 16 + 4 * lg] = o;
        }
    }
}

extern "C" void kernel_launch(void* const* d_in, const int* in_sizes, int n_in,
                              void* d_out, int out_size, void* d_ws, size_t ws_size,
                              hipStream_t stream) {
    const float* q  = (const float*)d_in[0];
    const float* k  = (const float*)d_in[1];
    const float* v  = (const float*)d_in[2];
    const float* Wq = (const float*)d_in[4];
    const float* bq = (const float*)d_in[5];
    const float* Wk = (const float*)d_in[6];
    const float* bk = (const float*)d_in[7];
    const float* Wv = (const float*)d_in[8];
    const float* bv = (const float*)d_in[9];
    const float* Wo = (const float*)d_in[10];
    const float* bo = (const float*)d_in[11];

    const size_t NEL = (size_t)4 * SEQ * DM;  // 8,388,608 elems per buffer
    const size_t WEL = (size_t)DM * DM;       // 1,048,576 elems per weight
    unsigned short* Qp  = (unsigned short*)d_ws;
    unsigned short* Kp  = Qp + NEL;
    unsigned short* Vp  = Kp + NEL;   // attn output Xp
    unsigned short* Vt  = Vp + NEL;
    unsigned short* Wob = Vt + NEL;
    unsigned short* Xp  = Vp;
    unsigned short* Wqb = (unsigned short*)d_out;  // d_out scratch until final GEMM
    unsigned short* Wkb = Wqb + WEL;
    unsigned short* Wvb = Wkb + WEL;

    hipLaunchKernelGGL(cvt_w, dim3(1024, 4), dim3(256), 0, stream, Wq, Wk, Wv, Wo,
                       Wqb, Wkb, Wvb, Wob);
    hipLaunchKernelGGL((gemm_bt<false, 0>), dim3(512), dim3(512), 0, stream,
                       (const void*)q, Wqb, bq, (void*)Qp, QSCALE);
    hipLaunchKernelGGL((gemm_bt<false, 0>), dim3(512), dim3(512), 0, stream,
                       (const void*)k, Wkb, bk, (void*)Kp, 1.0f);
    hipLaunchKernelGGL((gemm_bt<false, 2>), dim3(512), dim3(512), 0, stream,
                       (const void*)v, Wvb, bv, (void*)Vt, 1.0f);
    hipLaunchKernelGGL(attn, dim3(1024), dim3(256), 0, stream, Qp, Kp, Vt, Xp);
    hipLaunchKernelGGL((gemm_bt<true, 1>), dim3(512), dim3(512), 0, stream,
                       (const void*)Xp, Wob, bo, d_out, 1.0f);
}